// Round 3
// baseline (10975.294 us; speedup 1.0000x reference)
//
#include <hip/hip_runtime.h>
#include <hip/hip_bf16.h>

#define D_MODEL 1024
#define N_HEADS 16
#define D_HEAD  64
#define D_FF    4096
#define BATCH   4
#define SEQ     2048
#define ROWS    (BATCH*SEQ)   // 8192
#define LN_EPS  1e-5f

typedef __bf16 bf16;
typedef __bf16 bf16x8 __attribute__((ext_vector_type(8)));
typedef float  f32x4  __attribute__((ext_vector_type(4)));

// ---------------- fp32 -> bf16 convert (weights) ----------------
__global__ __launch_bounds__(256) void f2b_kernel(const float* __restrict__ src,
                                                  bf16* __restrict__ dst, int n) {
    int i = blockIdx.x * 256 + threadIdx.x;
    int stride = gridDim.x * 256;
    for (; i < n; i += stride) dst[i] = (bf16)src[i];
}

// ---------------- LayerNorm: fp32 in -> bf16 out, one block per row ----------------
__global__ __launch_bounds__(256) void ln_kernel(const float* __restrict__ x,
                                                 const float* __restrict__ gamma,
                                                 const float* __restrict__ beta,
                                                 bf16* __restrict__ out) {
    const int row = blockIdx.x;
    const int tid = threadIdx.x;
    const float* xr = x + (size_t)row * D_MODEL;

    float vals[4];
    float s = 0.f, ss = 0.f;
#pragma unroll
    for (int t = 0; t < 4; ++t) {
        float v = xr[tid + t * 256];
        vals[t] = v;
        s += v;
        ss += v * v;
    }
#pragma unroll
    for (int off = 32; off > 0; off >>= 1) {
        s  += __shfl_xor(s, off, 64);
        ss += __shfl_xor(ss, off, 64);
    }
    __shared__ float sbuf[4], ssbuf[4];
    const int wave = tid >> 6;
    if ((tid & 63) == 0) { sbuf[wave] = s; ssbuf[wave] = ss; }
    __syncthreads();
    s  = sbuf[0] + sbuf[1] + sbuf[2] + sbuf[3];
    ss = ssbuf[0] + ssbuf[1] + ssbuf[2] + ssbuf[3];

    const float mean = s * (1.f / D_MODEL);
    const float var  = ss * (1.f / D_MODEL) - mean * mean;
    const float inv  = rsqrtf(var + LN_EPS);

    bf16* orow = out + (size_t)row * D_MODEL;
#pragma unroll
    for (int t = 0; t < 4; ++t) {
        int c = tid + t * 256;
        orow[c] = (bf16)(gamma[c] * ((vals[t] - mean) * inv) + beta[c]);
    }
}

// ---------------- GELU (tanh approx, matches reference) ----------------
__device__ __forceinline__ float gelu_f(float x) {
    float c = x * x * x;
    return 0.5f * x * (1.f + tanhf(0.7978845608f * (x + 0.044715f * c)));
}

// ---------------- GEMM: C[M,N] = A[M,K] @ W[N,K]^T (+epilogue) ----------------
// EPI: 0 = plain store, 1 = gelu, 2 = add fp32 ADD[m*N+n] (residual)
// OutT: bf16 (activations) or float (residual / final output)
template <int EPI, typename OutT>
__global__ __launch_bounds__(256) void gemm_bt(const bf16* __restrict__ A,
                                               const bf16* __restrict__ W,
                                               OutT* __restrict__ C,
                                               const float* __restrict__ ADD,
                                               int M, int N, int K) {
    const int wave = threadIdx.x >> 6;
    const int lane = threadIdx.x & 63;
    const int quad = lane >> 4;
    const int l16  = lane & 15;

    const int n0 = blockIdx.x * 64 + wave * 16;
    const int m0 = blockIdx.y * 64;

    const bf16* a_ptr = A + (size_t)(m0 + l16) * K + quad * 8;
    const bf16* b_ptr = W + (size_t)(n0 + l16) * K + quad * 8;
    const size_t aStride16 = (size_t)16 * K;

    f32x4 acc[4] = {(f32x4)(0.f), (f32x4)(0.f), (f32x4)(0.f), (f32x4)(0.f)};

    for (int k = 0; k < K; k += 32) {
        bf16x8 b  = *reinterpret_cast<const bf16x8*>(b_ptr);
        bf16x8 a0 = *reinterpret_cast<const bf16x8*>(a_ptr);
        bf16x8 a1 = *reinterpret_cast<const bf16x8*>(a_ptr + aStride16);
        bf16x8 a2 = *reinterpret_cast<const bf16x8*>(a_ptr + 2 * aStride16);
        bf16x8 a3 = *reinterpret_cast<const bf16x8*>(a_ptr + 3 * aStride16);
        acc[0] = __builtin_amdgcn_mfma_f32_16x16x32_bf16(a0, b, acc[0], 0, 0, 0);
        acc[1] = __builtin_amdgcn_mfma_f32_16x16x32_bf16(a1, b, acc[1], 0, 0, 0);
        acc[2] = __builtin_amdgcn_mfma_f32_16x16x32_bf16(a2, b, acc[2], 0, 0, 0);
        acc[3] = __builtin_amdgcn_mfma_f32_16x16x32_bf16(a3, b, acc[3], 0, 0, 0);
        a_ptr += 32;
        b_ptr += 32;
    }

    const int n = n0 + l16;
#pragma unroll
    for (int s = 0; s < 4; ++s) {
        const int mbase = m0 + s * 16 + quad * 4;
#pragma unroll
        for (int r = 0; r < 4; ++r) {
            const int m = mbase + r;
            float v = acc[s][r];
            const size_t idx = (size_t)m * N + n;
            if (EPI == 1) v = gelu_f(v);
            if (EPI == 2) v += ADD[idx];
            C[idx] = (OutT)v;
        }
    }
}

// ---------------- Causal attention: one wave per query, lane = head-dim ----------------
__global__ __launch_bounds__(256) void attn_kernel(const bf16* __restrict__ q,
                                                   const bf16* __restrict__ k,
                                                   const bf16* __restrict__ v,
                                                   bf16* __restrict__ o) {
    const int wid  = (blockIdx.x << 2) + (threadIdx.x >> 6);
    const int lane = threadIdx.x & 63;
    const int b    = wid / (N_HEADS * SEQ);
    const int rem  = wid % (N_HEADS * SEQ);
    const int h    = rem / SEQ;
    const int qpos = rem % SEQ;

    const size_t qoff = (size_t)(b * SEQ + qpos) * D_MODEL + h * D_HEAD + lane;
    const float ql = (float)q[qoff] * 0.125f;  // 1/sqrt(64)

    const bf16* kp = k + (size_t)(b * SEQ) * D_MODEL + h * D_HEAD + lane;
    const bf16* vp = v + (size_t)(b * SEQ) * D_MODEL + h * D_HEAD + lane;

    float m = -1e30f, l = 0.f, oacc = 0.f;
    for (int j = 0; j <= qpos; ++j) {
        float kj = (float)kp[0];
        float vj = (float)vp[0];
        float d = ql * kj;
#pragma unroll
        for (int off = 32; off > 0; off >>= 1) d += __shfl_xor(d, off, 64);
        float mn = fmaxf(m, d);
        float alpha = __expf(m - mn);
        float p = __expf(d - mn);
        l = l * alpha + p;
        oacc = oacc * alpha + p * vj;
        m = mn;
        kp += D_MODEL;
        vp += D_MODEL;
    }
    o[qoff] = (bf16)(oacc / l);
}

// ---------------- launch ----------------
// fp32 I/O per the reference. Workspace (88 MB, lifetime-aliased):
//   [0,24 MB)  : bf16 weight copies wq|wk|wv|wo|fc1|fc2 (persist whole launch)
//   [24,40 MB) : n1 bf16 -> attn bf16 -> hid bf16 chunks
//   [40,72 MB) : q bf16 | k bf16 -> resid fp32 (32 MB)
//   [72,88 MB) : v bf16 -> n2 bf16
extern "C" void kernel_launch(void* const* d_in, const int* in_sizes, int n_in,
                              void* d_out, int out_size, void* d_ws, size_t ws_size,
                              hipStream_t stream) {
    const float* x      = (const float*)d_in[0];
    const float* gamma1 = (const float*)d_in[1];
    const float* beta1  = (const float*)d_in[2];
    const float* wq     = (const float*)d_in[3];
    const float* wk     = (const float*)d_in[4];
    const float* wv     = (const float*)d_in[5];
    const float* wo     = (const float*)d_in[6];
    const float* gamma2 = (const float*)d_in[7];
    const float* beta2  = (const float*)d_in[8];
    const float* fc1    = (const float*)d_in[9];
    const float* fc2    = (const float*)d_in[10];
    float* out = (float*)d_out;

    const size_t WSMALL = (size_t)N_HEADS * D_HEAD * D_MODEL;  // 1,048,576
    const size_t WFF    = (size_t)D_FF * D_MODEL;              // 4,194,304
    const size_t RD     = (size_t)ROWS * D_MODEL;              // 8,388,608

    char* wsb = (char*)d_ws;
    bf16* wq_b  = (bf16*)(wsb);
    bf16* wk_b  = wq_b + WSMALL;
    bf16* wv_b  = wk_b + WSMALL;
    bf16* wo_b  = wv_b + WSMALL;
    bf16* fc1_b = wo_b + WSMALL;
    bf16* fc2_b = fc1_b + WFF;            // ends at 24 MB
    bf16* slotA = fc2_b + WFF;            // 16 MB region: n1 -> attn -> hid chunk
    char* slotB = (char*)(slotA + RD);    // 32 MB region: q|k -> resid fp32
    bf16* qb    = (bf16*)slotB;
    bf16* kb    = qb + RD;
    float* resid = (float*)slotB;
    bf16* vb    = kb + RD;                // 16 MB region: v -> n2
    bf16* n2    = vb;

    bf16* n1    = slotA;
    bf16* attnb = slotA;
    bf16* hid   = slotA;

    // weight conversion fp32 -> bf16
    f2b_kernel<<<1024, 256, 0, stream>>>(wq,  wq_b,  (int)WSMALL);
    f2b_kernel<<<1024, 256, 0, stream>>>(wk,  wk_b,  (int)WSMALL);
    f2b_kernel<<<1024, 256, 0, stream>>>(wv,  wv_b,  (int)WSMALL);
    f2b_kernel<<<1024, 256, 0, stream>>>(wo,  wo_b,  (int)WSMALL);
    f2b_kernel<<<1024, 256, 0, stream>>>(fc1, fc1_b, (int)WFF);
    f2b_kernel<<<1024, 256, 0, stream>>>(fc2, fc2_b, (int)WFF);

    // LN1: x fp32 -> n1 bf16
    ln_kernel<<<ROWS, 256, 0, stream>>>(x, gamma1, beta1, n1);
    // Q,K,V projections: [8192,1024] = n1 @ w{q,k,v}^T  (bf16 out)
    gemm_bt<0, bf16><<<dim3(D_MODEL / 64, ROWS / 64), 256, 0, stream>>>(n1, wq_b, qb, nullptr, ROWS, D_MODEL, D_MODEL);
    gemm_bt<0, bf16><<<dim3(D_MODEL / 64, ROWS / 64), 256, 0, stream>>>(n1, wk_b, kb, nullptr, ROWS, D_MODEL, D_MODEL);
    gemm_bt<0, bf16><<<dim3(D_MODEL / 64, ROWS / 64), 256, 0, stream>>>(n1, wv_b, vb, nullptr, ROWS, D_MODEL, D_MODEL);
    // causal attention: q,k,v -> attn (slotA; n1 dead)
    attn_kernel<<<(BATCH * N_HEADS * SEQ) / 4, 256, 0, stream>>>(qb, kb, vb, attnb);
    // resid(fp32) = x + attn @ wo^T  (overwrites q|k region; both dead)
    gemm_bt<2, float><<<dim3(D_MODEL / 64, ROWS / 64), 256, 0, stream>>>(attnb, wo_b, resid, x, ROWS, D_MODEL, D_MODEL);
    // LN2: resid fp32 -> n2 bf16 (overwrites v; dead)
    ln_kernel<<<ROWS, 256, 0, stream>>>(resid, gamma2, beta2, n2);

    // MLP in 4 row-chunks of 2048; hid chunk = 2048x4096 bf16 = 16 MB in slotA (attn dead)
    const int CHUNK = 2048;
    for (int c = 0; c < ROWS / CHUNK; ++c) {
        const bf16*  n2c    = n2    + (size_t)c * CHUNK * D_MODEL;
        const float* residc = resid + (size_t)c * CHUNK * D_MODEL;
        float*       outc   = out   + (size_t)c * CHUNK * D_MODEL;
        // hid = gelu(n2c @ fc1^T)   [2048, 4096] bf16
        gemm_bt<1, bf16><<<dim3(D_FF / 64, CHUNK / 64), 256, 0, stream>>>(n2c, fc1_b, hid, nullptr, CHUNK, D_FF, D_MODEL);
        // outc(fp32) = residc + hid @ fc2^T   [2048, 1024]
        gemm_bt<2, float><<<dim3(D_MODEL / 64, CHUNK / 64), 256, 0, stream>>>(hid, fc2_b, outc, residc, CHUNK, D_MODEL, D_FF);
    }
}

// Round 4
// 2341.400 us; speedup vs baseline: 4.6875x; 4.6875x over previous
//
#include <hip/hip_runtime.h>
#include <hip/hip_bf16.h>

#define D_MODEL 1024
#define N_HEADS 16
#define D_HEAD  64
#define D_FF    4096
#define BATCH   4
#define SEQ     2048
#define ROWS    (BATCH*SEQ)   // 8192
#define LN_EPS  1e-5f

typedef __bf16 bf16;
typedef __bf16 bf16x8 __attribute__((ext_vector_type(8)));
typedef float  f32x4  __attribute__((ext_vector_type(4)));

// ---------------- fp32 -> bf16 convert (weights) ----------------
__global__ __launch_bounds__(256) void f2b_kernel(const float* __restrict__ src,
                                                  bf16* __restrict__ dst, int n) {
    int i = blockIdx.x * 256 + threadIdx.x;
    int stride = gridDim.x * 256;
    for (; i < n; i += stride) dst[i] = (bf16)src[i];
}

// ---------------- LayerNorm: fp32 in -> bf16 out, one block per row ----------------
__global__ __launch_bounds__(256) void ln_kernel(const float* __restrict__ x,
                                                 const float* __restrict__ gamma,
                                                 const float* __restrict__ beta,
                                                 bf16* __restrict__ out) {
    const int row = blockIdx.x;
    const int tid = threadIdx.x;
    const float* xr = x + (size_t)row * D_MODEL;

    float vals[4];
    float s = 0.f, ss = 0.f;
#pragma unroll
    for (int t = 0; t < 4; ++t) {
        float v = xr[tid + t * 256];
        vals[t] = v;
        s += v;
        ss += v * v;
    }
#pragma unroll
    for (int off = 32; off > 0; off >>= 1) {
        s  += __shfl_xor(s, off, 64);
        ss += __shfl_xor(ss, off, 64);
    }
    __shared__ float sbuf[4], ssbuf[4];
    const int wave = tid >> 6;
    if ((tid & 63) == 0) { sbuf[wave] = s; ssbuf[wave] = ss; }
    __syncthreads();
    s  = sbuf[0] + sbuf[1] + sbuf[2] + sbuf[3];
    ss = ssbuf[0] + ssbuf[1] + ssbuf[2] + ssbuf[3];

    const float mean = s * (1.f / D_MODEL);
    const float var  = ss * (1.f / D_MODEL) - mean * mean;
    const float inv  = rsqrtf(var + LN_EPS);

    bf16* orow = out + (size_t)row * D_MODEL;
#pragma unroll
    for (int t = 0; t < 4; ++t) {
        int c = tid + t * 256;
        orow[c] = (bf16)(gamma[c] * ((vals[t] - mean) * inv) + beta[c]);
    }
}

// ---------------- GELU (tanh approx, matches reference) ----------------
__device__ __forceinline__ float gelu_f(float x) {
    float c = x * x * x;
    return 0.5f * x * (1.f + tanhf(0.7978845608f * (x + 0.044715f * c)));
}

// ---------------- GEMM: C[M,N] = A[M,K] @ W[N,K]^T (+epilogue) ----------------
// EPI: 0 = plain store, 1 = gelu, 2 = add fp32 ADD (residual), 3 = store V transposed [B,H,dh,S]
template <int EPI, typename OutT>
__global__ __launch_bounds__(256) void gemm_bt(const bf16* __restrict__ A,
                                               const bf16* __restrict__ W,
                                               OutT* __restrict__ C,
                                               const float* __restrict__ ADD,
                                               int M, int N, int K) {
    const int wave = threadIdx.x >> 6;
    const int lane = threadIdx.x & 63;
    const int quad = lane >> 4;
    const int l16  = lane & 15;

    const int n0 = blockIdx.x * 64 + wave * 16;
    const int m0 = blockIdx.y * 64;

    const bf16* a_ptr = A + (size_t)(m0 + l16) * K + quad * 8;
    const bf16* b_ptr = W + (size_t)(n0 + l16) * K + quad * 8;
    const size_t aStride16 = (size_t)16 * K;

    f32x4 acc[4] = {(f32x4)(0.f), (f32x4)(0.f), (f32x4)(0.f), (f32x4)(0.f)};

    for (int k = 0; k < K; k += 32) {
        bf16x8 b  = *reinterpret_cast<const bf16x8*>(b_ptr);
        bf16x8 a0 = *reinterpret_cast<const bf16x8*>(a_ptr);
        bf16x8 a1 = *reinterpret_cast<const bf16x8*>(a_ptr + aStride16);
        bf16x8 a2 = *reinterpret_cast<const bf16x8*>(a_ptr + 2 * aStride16);
        bf16x8 a3 = *reinterpret_cast<const bf16x8*>(a_ptr + 3 * aStride16);
        acc[0] = __builtin_amdgcn_mfma_f32_16x16x32_bf16(a0, b, acc[0], 0, 0, 0);
        acc[1] = __builtin_amdgcn_mfma_f32_16x16x32_bf16(a1, b, acc[1], 0, 0, 0);
        acc[2] = __builtin_amdgcn_mfma_f32_16x16x32_bf16(a2, b, acc[2], 0, 0, 0);
        acc[3] = __builtin_amdgcn_mfma_f32_16x16x32_bf16(a3, b, acc[3], 0, 0, 0);
        a_ptr += 32;
        b_ptr += 32;
    }

    const int n = n0 + l16;
#pragma unroll
    for (int s = 0; s < 4; ++s) {
        const int mbase = m0 + s * 16 + quad * 4;
#pragma unroll
        for (int r = 0; r < 4; ++r) {
            const int m = mbase + r;
            float v = acc[s][r];
            if (EPI == 1) v = gelu_f(v);
            if (EPI == 3) {
                // V^T store: m = b*SEQ+s_pos, n = h*64+dh  ->  [((b*H+h)*64+dh)*SEQ + s_pos]
                const int bb = m >> 11, sp = m & (SEQ - 1);
                const int hh = n >> 6,  dh = n & 63;
                const size_t tidx = ((((size_t)bb * N_HEADS + hh) * D_HEAD + dh) << 11) + sp;
                C[tidx] = (OutT)v;
            } else {
                const size_t idx = (size_t)m * N + n;
                if (EPI == 2) v += ADD[idx];
                C[idx] = (OutT)v;
            }
        }
    }
}

// ---------------- Flash attention (causal), MFMA 16x16x32 ----------------
// Grid: (SEQ/64, BATCH*N_HEADS). Block: 4 waves; each wave owns 16 Q-rows.
// q,k: [B*S, D_MODEL] bf16 (head-sliced). vt: [B,H,dh,S] bf16. o: [B*S, D_MODEL] bf16.
__global__ __launch_bounds__(256) void flash_attn_kernel(const bf16* __restrict__ q,
                                                         const bf16* __restrict__ k,
                                                         const bf16* __restrict__ vt,
                                                         bf16* __restrict__ o) {
    const int qtile = blockIdx.x;          // 0..31
    const int bh    = blockIdx.y;          // 0..63
    const int b     = bh >> 4;
    const int h     = bh & 15;
    const int wave  = threadIdx.x >> 6;
    const int lane  = threadIdx.x & 63;
    const int quad  = lane >> 4;
    const int l16   = lane & 15;

    __shared__ bf16 pbuf[4][16][68];       // +4 pad: conflict-free writes

    const int q0 = qtile * 64 + wave * 16;               // wave's first q row (in-seq)
    const size_t qrow = (size_t)(b * SEQ + q0 + l16) * D_MODEL + h * D_HEAD;
    bf16x8 qf0 = *reinterpret_cast<const bf16x8*>(q + qrow + quad * 8);
    bf16x8 qf1 = *reinterpret_cast<const bf16x8*>(q + qrow + 32 + quad * 8);

    const bf16* kbase = k + (size_t)(b * SEQ) * D_MODEL + h * D_HEAD;
    const bf16* vbase = vt + ((size_t)(bh * D_HEAD) << 11);   // [dh][S]

    f32x4 o_acc[4] = {(f32x4)(0.f), (f32x4)(0.f), (f32x4)(0.f), (f32x4)(0.f)};
    float m_r[4] = {-1e30f, -1e30f, -1e30f, -1e30f};
    float l_r[4] = {0.f, 0.f, 0.f, 0.f};

    for (int jt = 0; jt <= qtile; ++jt) {
        const int j0 = jt * 64;
        // ---- S = Q @ K^T (16x64 per wave) ----
        f32x4 s_acc[4] = {(f32x4)(0.f), (f32x4)(0.f), (f32x4)(0.f), (f32x4)(0.f)};
#pragma unroll
        for (int nb = 0; nb < 4; ++nb) {
            const bf16* kr = kbase + (size_t)(j0 + nb * 16 + l16) * D_MODEL;
            bf16x8 kf0 = *reinterpret_cast<const bf16x8*>(kr + quad * 8);
            bf16x8 kf1 = *reinterpret_cast<const bf16x8*>(kr + 32 + quad * 8);
            s_acc[nb] = __builtin_amdgcn_mfma_f32_16x16x32_bf16(qf0, kf0, s_acc[nb], 0, 0, 0);
            s_acc[nb] = __builtin_amdgcn_mfma_f32_16x16x32_bf16(qf1, kf1, s_acc[nb], 0, 0, 0);
        }
        // ---- scale + causal mask (diagonal tile only) ----
        const bool diag = (jt == qtile);
        float sv[4][4];
#pragma unroll
        for (int nb = 0; nb < 4; ++nb) {
            const int key = j0 + nb * 16 + l16;
#pragma unroll
            for (int r = 0; r < 4; ++r) {
                float s = s_acc[nb][r] * 0.125f;
                if (diag && key > q0 + quad * 4 + r) s = -1e30f;
                sv[nb][r] = s;
            }
        }
        // ---- online softmax per row (rows live in one 16-lane quad) ----
#pragma unroll
        for (int r = 0; r < 4; ++r) {
            float mx = fmaxf(fmaxf(sv[0][r], sv[1][r]), fmaxf(sv[2][r], sv[3][r]));
#pragma unroll
            for (int off = 1; off < 16; off <<= 1) mx = fmaxf(mx, __shfl_xor(mx, off, 64));
            const float mn = fmaxf(m_r[r], mx);
            const float alpha = __expf(m_r[r] - mn);
            m_r[r] = mn;
            float rs = 0.f;
#pragma unroll
            for (int nb = 0; nb < 4; ++nb) {
                float p = __expf(sv[nb][r] - mn);
                rs += p;
                pbuf[wave][quad * 4 + r][nb * 16 + l16] = (bf16)p;
            }
#pragma unroll
            for (int off = 1; off < 16; off <<= 1) rs += __shfl_xor(rs, off, 64);
            l_r[r] = l_r[r] * alpha + rs;
#pragma unroll
            for (int nb = 0; nb < 4; ++nb) o_acc[nb][r] *= alpha;
        }
        // ---- O += P @ V  (P via LDS C->A layout round-trip; same-wave, no barrier) ----
        bf16x8 pf0 = *reinterpret_cast<const bf16x8*>(&pbuf[wave][l16][quad * 8]);
        bf16x8 pf1 = *reinterpret_cast<const bf16x8*>(&pbuf[wave][l16][32 + quad * 8]);
#pragma unroll
        for (int nb = 0; nb < 4; ++nb) {
            const bf16* vr = vbase + (((size_t)(nb * 16 + l16)) << 11) + j0;
            bf16x8 vf0 = *reinterpret_cast<const bf16x8*>(vr + quad * 8);
            bf16x8 vf1 = *reinterpret_cast<const bf16x8*>(vr + 32 + quad * 8);
            o_acc[nb] = __builtin_amdgcn_mfma_f32_16x16x32_bf16(pf0, vf0, o_acc[nb], 0, 0, 0);
            o_acc[nb] = __builtin_amdgcn_mfma_f32_16x16x32_bf16(pf1, vf1, o_acc[nb], 0, 0, 0);
        }
    }
    // ---- epilogue: O /= l, store ----
#pragma unroll
    for (int nb = 0; nb < 4; ++nb) {
#pragma unroll
        for (int r = 0; r < 4; ++r) {
            const int qrow_g = q0 + quad * 4 + r;
            o[(size_t)(b * SEQ + qrow_g) * D_MODEL + h * D_HEAD + nb * 16 + l16] =
                (bf16)(o_acc[nb][r] / l_r[r]);
        }
    }
}

// ---------------- launch ----------------
// fp32 I/O per the reference. Workspace (88 MB, lifetime-aliased):
//   [0,24 MB)  : bf16 weight copies wq|wk|wv|wo|fc1|fc2 (persist whole launch)
//   [24,40 MB) : n1 bf16 -> attn bf16 -> hid bf16 chunks
//   [40,72 MB) : q bf16 | k bf16 -> resid fp32 (32 MB)
//   [72,88 MB) : vT bf16 [B,H,dh,S] -> n2 bf16
extern "C" void kernel_launch(void* const* d_in, const int* in_sizes, int n_in,
                              void* d_out, int out_size, void* d_ws, size_t ws_size,
                              hipStream_t stream) {
    const float* x      = (const float*)d_in[0];
    const float* gamma1 = (const float*)d_in[1];
    const float* beta1  = (const float*)d_in[2];
    const float* wq     = (const float*)d_in[3];
    const float* wk     = (const float*)d_in[4];
    const float* wv     = (const float*)d_in[5];
    const float* wo     = (const float*)d_in[6];
    const float* gamma2 = (const float*)d_in[7];
    const float* beta2  = (const float*)d_in[8];
    const float* fc1    = (const float*)d_in[9];
    const float* fc2    = (const float*)d_in[10];
    float* out = (float*)d_out;

    const size_t WSMALL = (size_t)N_HEADS * D_HEAD * D_MODEL;  // 1,048,576
    const size_t WFF    = (size_t)D_FF * D_MODEL;              // 4,194,304
    const size_t RD     = (size_t)ROWS * D_MODEL;              // 8,388,608

    char* wsb = (char*)d_ws;
    bf16* wq_b  = (bf16*)(wsb);
    bf16* wk_b  = wq_b + WSMALL;
    bf16* wv_b  = wk_b + WSMALL;
    bf16* wo_b  = wv_b + WSMALL;
    bf16* fc1_b = wo_b + WSMALL;
    bf16* fc2_b = fc1_b + WFF;            // ends at 24 MB
    bf16* slotA = fc2_b + WFF;            // 16 MB: n1 -> attn -> hid chunk
    char* slotB = (char*)(slotA + RD);    // 32 MB: q|k -> resid fp32
    bf16* qb    = (bf16*)slotB;
    bf16* kb    = qb + RD;
    float* resid = (float*)slotB;
    bf16* vtb   = kb + RD;                // 16 MB: vT -> n2
    bf16* n2    = vtb;

    bf16* n1    = slotA;
    bf16* attnb = slotA;
    bf16* hid   = slotA;

    // weight conversion fp32 -> bf16
    f2b_kernel<<<1024, 256, 0, stream>>>(wq,  wq_b,  (int)WSMALL);
    f2b_kernel<<<1024, 256, 0, stream>>>(wk,  wk_b,  (int)WSMALL);
    f2b_kernel<<<1024, 256, 0, stream>>>(wv,  wv_b,  (int)WSMALL);
    f2b_kernel<<<1024, 256, 0, stream>>>(wo,  wo_b,  (int)WSMALL);
    f2b_kernel<<<1024, 256, 0, stream>>>(fc1, fc1_b, (int)WFF);
    f2b_kernel<<<1024, 256, 0, stream>>>(fc2, fc2_b, (int)WFF);

    // LN1: x fp32 -> n1 bf16
    ln_kernel<<<ROWS, 256, 0, stream>>>(x, gamma1, beta1, n1);
    // Q,K projections; V projection stores V^T [B,H,dh,S]
    gemm_bt<0, bf16><<<dim3(D_MODEL / 64, ROWS / 64), 256, 0, stream>>>(n1, wq_b, qb, nullptr, ROWS, D_MODEL, D_MODEL);
    gemm_bt<0, bf16><<<dim3(D_MODEL / 64, ROWS / 64), 256, 0, stream>>>(n1, wk_b, kb, nullptr, ROWS, D_MODEL, D_MODEL);
    gemm_bt<3, bf16><<<dim3(D_MODEL / 64, ROWS / 64), 256, 0, stream>>>(n1, wv_b, vtb, nullptr, ROWS, D_MODEL, D_MODEL);
    // flash attention: q,k,vT -> attn (slotA; n1 dead)
    flash_attn_kernel<<<dim3(SEQ / 64, BATCH * N_HEADS), 256, 0, stream>>>(qb, kb, vtb, attnb);
    // resid(fp32) = x + attn @ wo^T  (overwrites q|k region; both dead)
    gemm_bt<2, float><<<dim3(D_MODEL / 64, ROWS / 64), 256, 0, stream>>>(attnb, wo_b, resid, x, ROWS, D_MODEL, D_MODEL);
    // LN2: resid fp32 -> n2 bf16 (overwrites vT; dead)
    ln_kernel<<<ROWS, 256, 0, stream>>>(resid, gamma2, beta2, n2);

    // MLP in 4 row-chunks of 2048; hid chunk = 2048x4096 bf16 = 16 MB in slotA
    const int CHUNK = 2048;
    for (int c = 0; c < ROWS / CHUNK; ++c) {
        const bf16*  n2c    = n2    + (size_t)c * CHUNK * D_MODEL;
        const float* residc = resid + (size_t)c * CHUNK * D_MODEL;
        float*       outc   = out   + (size_t)c * CHUNK * D_MODEL;
        gemm_bt<1, bf16><<<dim3(D_FF / 64, CHUNK / 64), 256, 0, stream>>>(n2c, fc1_b, hid, nullptr, CHUNK, D_FF, D_MODEL);
        gemm_bt<2, float><<<dim3(D_MODEL / 64, CHUNK / 64), 256, 0, stream>>>(hid, fc2_b, outc, residc, CHUNK, D_MODEL, D_FF);
    }
}

// Round 5
// 2169.059 us; speedup vs baseline: 5.0599x; 1.0795x over previous
//
#include <hip/hip_runtime.h>
#include <hip/hip_bf16.h>

#define D_MODEL 1024
#define N_HEADS 16
#define D_HEAD  64
#define D_FF    4096
#define BATCH   4
#define SEQ     2048
#define ROWS    (BATCH*SEQ)   // 8192
#define LN_EPS  1e-5f

typedef __bf16 bf16;
typedef __bf16 bf16x8 __attribute__((ext_vector_type(8)));
typedef float  f32x4  __attribute__((ext_vector_type(4)));

// ---------------- fp32 -> bf16 convert (weights) ----------------
__global__ __launch_bounds__(256) void f2b_kernel(const float* __restrict__ src,
                                                  bf16* __restrict__ dst, int n) {
    int i = blockIdx.x * 256 + threadIdx.x;
    int stride = gridDim.x * 256;
    for (; i < n; i += stride) dst[i] = (bf16)src[i];
}

// ---------------- LayerNorm: fp32 in -> bf16 out, one block per row ----------------
__global__ __launch_bounds__(256) void ln_kernel(const float* __restrict__ x,
                                                 const float* __restrict__ gamma,
                                                 const float* __restrict__ beta,
                                                 bf16* __restrict__ out) {
    const int row = blockIdx.x;
    const int tid = threadIdx.x;
    const float* xr = x + (size_t)row * D_MODEL;

    float vals[4];
    float s = 0.f, ss = 0.f;
#pragma unroll
    for (int t = 0; t < 4; ++t) {
        float v = xr[tid + t * 256];
        vals[t] = v;
        s += v;
        ss += v * v;
    }
#pragma unroll
    for (int off = 32; off > 0; off >>= 1) {
        s  += __shfl_xor(s, off, 64);
        ss += __shfl_xor(ss, off, 64);
    }
    __shared__ float sbuf[4], ssbuf[4];
    const int wave = tid >> 6;
    if ((tid & 63) == 0) { sbuf[wave] = s; ssbuf[wave] = ss; }
    __syncthreads();
    s  = sbuf[0] + sbuf[1] + sbuf[2] + sbuf[3];
    ss = ssbuf[0] + ssbuf[1] + ssbuf[2] + ssbuf[3];

    const float mean = s * (1.f / D_MODEL);
    const float var  = ss * (1.f / D_MODEL) - mean * mean;
    const float inv  = rsqrtf(var + LN_EPS);

    bf16* orow = out + (size_t)row * D_MODEL;
#pragma unroll
    for (int t = 0; t < 4; ++t) {
        int c = tid + t * 256;
        orow[c] = (bf16)(gamma[c] * ((vals[t] - mean) * inv) + beta[c]);
    }
}

// ---------------- GELU (tanh approx, matches reference) ----------------
__device__ __forceinline__ float gelu_f(float x) {
    float c = x * x * x;
    return 0.5f * x * (1.f + tanhf(0.7978845608f * (x + 0.044715f * c)));
}

// ---------------- GEMM: C[M,N] = A[M,K] @ W[N,K]^T (+epilogue) ----------------
// EPI: 0 = plain store, 1 = gelu, 2 = add fp32 ADD (residual),
//      3 = store transposed [B,H,dh,S] via LDS (coalesced along S)
template <int EPI, typename OutT>
__global__ __launch_bounds__(256) void gemm_bt(const bf16* __restrict__ A,
                                               const bf16* __restrict__ W,
                                               OutT* __restrict__ C,
                                               const float* __restrict__ ADD,
                                               int M, int N, int K) {
    // LDS only used by EPI==3 (64x64 tile, row stride 72 keeps rows 16B-aligned)
    __shared__ bf16 sCt[EPI == 3 ? 64 * 72 : 1];

    const int wave = threadIdx.x >> 6;
    const int lane = threadIdx.x & 63;
    const int quad = lane >> 4;
    const int l16  = lane & 15;

    const int n0 = blockIdx.x * 64 + wave * 16;
    const int m0 = blockIdx.y * 64;

    const bf16* a_ptr = A + (size_t)(m0 + l16) * K + quad * 8;
    const bf16* b_ptr = W + (size_t)(n0 + l16) * K + quad * 8;
    const size_t aStride16 = (size_t)16 * K;

    f32x4 acc[4] = {(f32x4)(0.f), (f32x4)(0.f), (f32x4)(0.f), (f32x4)(0.f)};

    for (int k = 0; k < K; k += 32) {
        bf16x8 b  = *reinterpret_cast<const bf16x8*>(b_ptr);
        bf16x8 a0 = *reinterpret_cast<const bf16x8*>(a_ptr);
        bf16x8 a1 = *reinterpret_cast<const bf16x8*>(a_ptr + aStride16);
        bf16x8 a2 = *reinterpret_cast<const bf16x8*>(a_ptr + 2 * aStride16);
        bf16x8 a3 = *reinterpret_cast<const bf16x8*>(a_ptr + 3 * aStride16);
        acc[0] = __builtin_amdgcn_mfma_f32_16x16x32_bf16(a0, b, acc[0], 0, 0, 0);
        acc[1] = __builtin_amdgcn_mfma_f32_16x16x32_bf16(a1, b, acc[1], 0, 0, 0);
        acc[2] = __builtin_amdgcn_mfma_f32_16x16x32_bf16(a2, b, acc[2], 0, 0, 0);
        acc[3] = __builtin_amdgcn_mfma_f32_16x16x32_bf16(a3, b, acc[3], 0, 0, 0);
        a_ptr += 32;
        b_ptr += 32;
    }

    const int n = n0 + l16;
#pragma unroll
    for (int s = 0; s < 4; ++s) {
        const int mbase = m0 + s * 16 + quad * 4;
#pragma unroll
        for (int r = 0; r < 4; ++r) {
            const int m = mbase + r;
            float v = acc[s][r];
            if (EPI == 3) {
                // stage to LDS transposed: sCt[n_loc][m_loc]
                const int n_loc = wave * 16 + l16;
                const int m_loc = s * 16 + quad * 4 + r;
                sCt[n_loc * 72 + m_loc] = (bf16)v;
            } else {
                if (EPI == 1) v = gelu_f(v);
                const size_t idx = (size_t)m * N + n;
                if (EPI == 2) v += ADD[idx];
                C[idx] = (OutT)v;
            }
        }
    }
    if constexpr (EPI == 3) {
        __syncthreads();
        // block-wide coalesced store: [B,H,dh,S], contiguous along S (= m)
        const int bb = m0 >> 11;          // m0 / SEQ
        const int sp0 = m0 & (SEQ - 1);
        const int hh = (blockIdx.x * 64) >> 6;   // N==D_MODEL: one head per x-tile
#pragma unroll
        for (int i = 0; i < 2; ++i) {
            const int c = threadIdx.x + 256 * i;
            const int n_loc = c >> 3;
            const int mc = c & 7;
            bf16x8 vv = *reinterpret_cast<const bf16x8*>(&sCt[n_loc * 72 + mc * 8]);
            const size_t tidx = ((((size_t)bb * N_HEADS + hh) * D_HEAD + n_loc) << 11)
                                + sp0 + mc * 8;
            *reinterpret_cast<bf16x8*>(&((bf16*)C)[tidx]) = vv;
        }
    }
}

// ---------------- Flash attention (causal), MFMA 16x16x32 ----------------
// Grid: (SEQ/128, BATCH*N_HEADS). Block i handles qtiles {i, 31-i} -> uniform
// 33 K-tile iterations per block. Block: 4 waves; each wave owns 16 Q-rows.
// q,k: [B*S, D_MODEL] bf16 (head-sliced). vt: [B,H,dh,S] bf16. o: [B*S, D_MODEL] bf16.
__global__ __launch_bounds__(256) void flash_attn_kernel(const bf16* __restrict__ q,
                                                         const bf16* __restrict__ k,
                                                         const bf16* __restrict__ vt,
                                                         bf16* __restrict__ o) {
    const int pairIdx = blockIdx.x;        // 0..15
    const int bh    = blockIdx.y;          // 0..63
    const int b     = bh >> 4;
    const int h     = bh & 15;
    const int wave  = threadIdx.x >> 6;
    const int lane  = threadIdx.x & 63;
    const int quad  = lane >> 4;
    const int l16   = lane & 15;

    __shared__ bf16 pbuf[4][16][68];       // +4 pad: conflict-light writes

    const bf16* kbase = k + (size_t)(b * SEQ) * D_MODEL + h * D_HEAD;
    const bf16* vbase = vt + ((size_t)(bh * D_HEAD) << 11);   // [dh][S]

    for (int half = 0; half < 2; ++half) {
        const int qtile = (half == 0) ? pairIdx : (SEQ / 64 - 1) - pairIdx;
        const int q0 = qtile * 64 + wave * 16;           // wave's first q row
        const size_t qrow = (size_t)(b * SEQ + q0 + l16) * D_MODEL + h * D_HEAD;
        bf16x8 qf0 = *reinterpret_cast<const bf16x8*>(q + qrow + quad * 8);
        bf16x8 qf1 = *reinterpret_cast<const bf16x8*>(q + qrow + 32 + quad * 8);

        f32x4 o_acc[4] = {(f32x4)(0.f), (f32x4)(0.f), (f32x4)(0.f), (f32x4)(0.f)};
        float m_r[4] = {-1e30f, -1e30f, -1e30f, -1e30f};
        float l_r[4] = {0.f, 0.f, 0.f, 0.f};

        for (int jt = 0; jt <= qtile; ++jt) {
            const int j0 = jt * 64;
            // ---- S = Q @ K^T (16x64 per wave) ----
            f32x4 s_acc[4] = {(f32x4)(0.f), (f32x4)(0.f), (f32x4)(0.f), (f32x4)(0.f)};
#pragma unroll
            for (int nb = 0; nb < 4; ++nb) {
                const bf16* kr = kbase + (size_t)(j0 + nb * 16 + l16) * D_MODEL;
                bf16x8 kf0 = *reinterpret_cast<const bf16x8*>(kr + quad * 8);
                bf16x8 kf1 = *reinterpret_cast<const bf16x8*>(kr + 32 + quad * 8);
                s_acc[nb] = __builtin_amdgcn_mfma_f32_16x16x32_bf16(qf0, kf0, s_acc[nb], 0, 0, 0);
                s_acc[nb] = __builtin_amdgcn_mfma_f32_16x16x32_bf16(qf1, kf1, s_acc[nb], 0, 0, 0);
            }
            // ---- scale + causal mask (diagonal tile only) ----
            const bool diag = (jt == qtile);
            float sv[4][4];
#pragma unroll
            for (int nb = 0; nb < 4; ++nb) {
                const int key = j0 + nb * 16 + l16;
#pragma unroll
                for (int r = 0; r < 4; ++r) {
                    float s = s_acc[nb][r] * 0.125f;
                    if (diag && key > q0 + quad * 4 + r) s = -1e30f;
                    sv[nb][r] = s;
                }
            }
            // ---- online softmax per row (rows live in one 16-lane quad) ----
#pragma unroll
            for (int r = 0; r < 4; ++r) {
                float mx = fmaxf(fmaxf(sv[0][r], sv[1][r]), fmaxf(sv[2][r], sv[3][r]));
#pragma unroll
                for (int off = 1; off < 16; off <<= 1) mx = fmaxf(mx, __shfl_xor(mx, off, 64));
                const float mn = fmaxf(m_r[r], mx);
                const float alpha = __expf(m_r[r] - mn);
                m_r[r] = mn;
                float rs = 0.f;
#pragma unroll
                for (int nb = 0; nb < 4; ++nb) {
                    float p = __expf(sv[nb][r] - mn);
                    rs += p;
                    pbuf[wave][quad * 4 + r][nb * 16 + l16] = (bf16)p;
                }
#pragma unroll
                for (int off = 1; off < 16; off <<= 1) rs += __shfl_xor(rs, off, 64);
                l_r[r] = l_r[r] * alpha + rs;
#pragma unroll
                for (int nb = 0; nb < 4; ++nb) o_acc[nb][r] *= alpha;
            }
            // ---- O += P @ V  (P via LDS C->A layout round-trip; same-wave) ----
            bf16x8 pf0 = *reinterpret_cast<const bf16x8*>(&pbuf[wave][l16][quad * 8]);
            bf16x8 pf1 = *reinterpret_cast<const bf16x8*>(&pbuf[wave][l16][32 + quad * 8]);
#pragma unroll
            for (int nb = 0; nb < 4; ++nb) {
                const bf16* vr = vbase + (((size_t)(nb * 16 + l16)) << 11) + j0;
                bf16x8 vf0 = *reinterpret_cast<const bf16x8*>(vr + quad * 8);
                bf16x8 vf1 = *reinterpret_cast<const bf16x8*>(vr + 32 + quad * 8);
                o_acc[nb] = __builtin_amdgcn_mfma_f32_16x16x32_bf16(pf0, vf0, o_acc[nb], 0, 0, 0);
                o_acc[nb] = __builtin_amdgcn_mfma_f32_16x16x32_bf16(pf1, vf1, o_acc[nb], 0, 0, 0);
            }
        }
        // ---- epilogue: O /= l, store ----
#pragma unroll
        for (int nb = 0; nb < 4; ++nb) {
#pragma unroll
            for (int r = 0; r < 4; ++r) {
                const int qrow_g = q0 + quad * 4 + r;
                o[(size_t)(b * SEQ + qrow_g) * D_MODEL + h * D_HEAD + nb * 16 + l16] =
                    (bf16)(o_acc[nb][r] / l_r[r]);
            }
        }
    }
}

// ---------------- launch ----------------
// fp32 I/O per the reference. Workspace (88 MB, lifetime-aliased):
//   [0,24 MB)  : bf16 weight copies wq|wk|wv|wo|fc1|fc2 (persist whole launch)
//   [24,40 MB) : n1 bf16 -> attn bf16 -> hid bf16 chunks
//   [40,72 MB) : q bf16 | k bf16 -> resid fp32 (32 MB)
//   [72,88 MB) : vT bf16 [B,H,dh,S] -> n2 bf16
extern "C" void kernel_launch(void* const* d_in, const int* in_sizes, int n_in,
                              void* d_out, int out_size, void* d_ws, size_t ws_size,
                              hipStream_t stream) {
    const float* x      = (const float*)d_in[0];
    const float* gamma1 = (const float*)d_in[1];
    const float* beta1  = (const float*)d_in[2];
    const float* wq     = (const float*)d_in[3];
    const float* wk     = (const float*)d_in[4];
    const float* wv     = (const float*)d_in[5];
    const float* wo     = (const float*)d_in[6];
    const float* gamma2 = (const float*)d_in[7];
    const float* beta2  = (const float*)d_in[8];
    const float* fc1    = (const float*)d_in[9];
    const float* fc2    = (const float*)d_in[10];
    float* out = (float*)d_out;

    const size_t WSMALL = (size_t)N_HEADS * D_HEAD * D_MODEL;  // 1,048,576
    const size_t WFF    = (size_t)D_FF * D_MODEL;              // 4,194,304
    const size_t RD     = (size_t)ROWS * D_MODEL;              // 8,388,608

    char* wsb = (char*)d_ws;
    bf16* wq_b  = (bf16*)(wsb);
    bf16* wk_b  = wq_b + WSMALL;
    bf16* wv_b  = wk_b + WSMALL;
    bf16* wo_b  = wv_b + WSMALL;
    bf16* fc1_b = wo_b + WSMALL;
    bf16* fc2_b = fc1_b + WFF;            // ends at 24 MB
    bf16* slotA = fc2_b + WFF;            // 16 MB: n1 -> attn -> hid chunk
    char* slotB = (char*)(slotA + RD);    // 32 MB: q|k -> resid fp32
    bf16* qb    = (bf16*)slotB;
    bf16* kb    = qb + RD;
    float* resid = (float*)slotB;
    bf16* vtb   = kb + RD;                // 16 MB: vT -> n2
    bf16* n2    = vtb;

    bf16* n1    = slotA;
    bf16* attnb = slotA;
    bf16* hid   = slotA;

    // weight conversion fp32 -> bf16
    f2b_kernel<<<1024, 256, 0, stream>>>(wq,  wq_b,  (int)WSMALL);
    f2b_kernel<<<1024, 256, 0, stream>>>(wk,  wk_b,  (int)WSMALL);
    f2b_kernel<<<1024, 256, 0, stream>>>(wv,  wv_b,  (int)WSMALL);
    f2b_kernel<<<1024, 256, 0, stream>>>(wo,  wo_b,  (int)WSMALL);
    f2b_kernel<<<1024, 256, 0, stream>>>(fc1, fc1_b, (int)WFF);
    f2b_kernel<<<1024, 256, 0, stream>>>(fc2, fc2_b, (int)WFF);

    // LN1: x fp32 -> n1 bf16
    ln_kernel<<<ROWS, 256, 0, stream>>>(x, gamma1, beta1, n1);
    // Q,K projections; V projection stores V^T [B,H,dh,S] (LDS-transposed, coalesced)
    gemm_bt<0, bf16><<<dim3(D_MODEL / 64, ROWS / 64), 256, 0, stream>>>(n1, wq_b, qb, nullptr, ROWS, D_MODEL, D_MODEL);
    gemm_bt<0, bf16><<<dim3(D_MODEL / 64, ROWS / 64), 256, 0, stream>>>(n1, wk_b, kb, nullptr, ROWS, D_MODEL, D_MODEL);
    gemm_bt<3, bf16><<<dim3(D_MODEL / 64, ROWS / 64), 256, 0, stream>>>(n1, wv_b, vtb, nullptr, ROWS, D_MODEL, D_MODEL);
    // flash attention (work-balanced): q,k,vT -> attn (slotA; n1 dead)
    flash_attn_kernel<<<dim3(SEQ / 128, BATCH * N_HEADS), 256, 0, stream>>>(qb, kb, vtb, attnb);
    // resid(fp32) = x + attn @ wo^T  (overwrites q|k region; both dead)
    gemm_bt<2, float><<<dim3(D_MODEL / 64, ROWS / 64), 256, 0, stream>>>(attnb, wo_b, resid, x, ROWS, D_MODEL, D_MODEL);
    // LN2: resid fp32 -> n2 bf16 (overwrites vT; dead)
    ln_kernel<<<ROWS, 256, 0, stream>>>(resid, gamma2, beta2, n2);

    // MLP in 4 row-chunks of 2048; hid chunk = 2048x4096 bf16 = 16 MB in slotA
    const int CHUNK = 2048;
    for (int c = 0; c < ROWS / CHUNK; ++c) {
        const bf16*  n2c    = n2    + (size_t)c * CHUNK * D_MODEL;
        const float* residc = resid + (size_t)c * CHUNK * D_MODEL;
        float*       outc   = out   + (size_t)c * CHUNK * D_MODEL;
        gemm_bt<1, bf16><<<dim3(D_FF / 64, CHUNK / 64), 256, 0, stream>>>(n2c, fc1_b, hid, nullptr, CHUNK, D_FF, D_MODEL);
        gemm_bt<2, float><<<dim3(D_MODEL / 64, CHUNK / 64), 256, 0, stream>>>(hid, fc2_b, outc, residc, CHUNK, D_MODEL, D_FF);
    }
}

// Round 6
// 922.228 us; speedup vs baseline: 11.9008x; 2.3520x over previous
//
#include <hip/hip_runtime.h>
#include <hip/hip_bf16.h>

#define D_MODEL 1024
#define N_HEADS 16
#define D_HEAD  64
#define D_FF    4096
#define BATCH   4
#define SEQ     2048
#define ROWS    (BATCH*SEQ)   // 8192
#define LN_EPS  1e-5f

typedef __bf16 bf16;
typedef __bf16 bf16x8 __attribute__((ext_vector_type(8)));
typedef float  f32x4  __attribute__((ext_vector_type(4)));

// ---- async global->LDS 16B copy: dst is WAVE-UNIFORM base, HW adds lane*16B ----
__device__ __forceinline__ void load16_lds(const bf16* g, bf16* l) {
#if defined(__has_builtin) && __has_builtin(__builtin_amdgcn_global_load_lds)
    __builtin_amdgcn_global_load_lds(
        (const __attribute__((address_space(1))) unsigned int*)g,
        (__attribute__((address_space(3))) unsigned int*)l,
        16, 0, 0);
#else
    const int lane = threadIdx.x & 63;
    ((bf16x8*)l)[lane] = *(const bf16x8*)g;
#endif
}

// ---------------- fp32 -> bf16 convert (weights) ----------------
__global__ __launch_bounds__(256) void f2b_kernel(const float* __restrict__ src,
                                                  bf16* __restrict__ dst, int n) {
    int i = blockIdx.x * 256 + threadIdx.x;
    int stride = gridDim.x * 256;
    for (; i < n; i += stride) dst[i] = (bf16)src[i];
}

// ---------------- LayerNorm: fp32 in -> bf16 out, one block per row ----------------
__global__ __launch_bounds__(256) void ln_kernel(const float* __restrict__ x,
                                                 const float* __restrict__ gamma,
                                                 const float* __restrict__ beta,
                                                 bf16* __restrict__ out) {
    const int row = blockIdx.x;
    const int tid = threadIdx.x;
    const float* xr = x + (size_t)row * D_MODEL;

    float vals[4];
    float s = 0.f, ss = 0.f;
#pragma unroll
    for (int t = 0; t < 4; ++t) {
        float v = xr[tid + t * 256];
        vals[t] = v;
        s += v;
        ss += v * v;
    }
#pragma unroll
    for (int off = 32; off > 0; off >>= 1) {
        s  += __shfl_xor(s, off, 64);
        ss += __shfl_xor(ss, off, 64);
    }
    __shared__ float sbuf[4], ssbuf[4];
    const int wave = tid >> 6;
    if ((tid & 63) == 0) { sbuf[wave] = s; ssbuf[wave] = ss; }
    __syncthreads();
    s  = sbuf[0] + sbuf[1] + sbuf[2] + sbuf[3];
    ss = ssbuf[0] + ssbuf[1] + ssbuf[2] + ssbuf[3];

    const float mean = s * (1.f / D_MODEL);
    const float var  = ss * (1.f / D_MODEL) - mean * mean;
    const float inv  = rsqrtf(var + LN_EPS);

    bf16* orow = out + (size_t)row * D_MODEL;
#pragma unroll
    for (int t = 0; t < 4; ++t) {
        int c = tid + t * 256;
        orow[c] = (bf16)(gamma[c] * ((vals[t] - mean) * inv) + beta[c]);
    }
}

// ---------------- GELU (tanh approx, matches reference) ----------------
__device__ __forceinline__ float gelu_f(float x) {
    float c = x * x * x;
    return 0.5f * x * (1.f + tanhf(0.7978845608f * (x + 0.044715f * c)));
}

// ---------------- GEMM m97-style: C[M,N] = A[M,K] @ W[N,K]^T (+epilogue) ----------------
// 256 threads = 4 waves; tile 128Mx128N; BK=32; global_load_lds width-16 staging.
// Wave w computes the 64x64 subtile (wm=w>>1, wn=w&1): 4x4 MFMA 16x16x32.
// EPI: 0 = plain store, 1 = gelu, 2 = v += ADD[idx] fp32 (C may alias ADD),
//      3 = store transposed [B,H,dh,S] (for V), coalesced along S via per-wave LDS.
template <int EPI, typename OutT>
__global__ __launch_bounds__(256) void gemm128(const bf16* __restrict__ A,
                                               const bf16* __restrict__ W,
                                               OutT* C,
                                               const float* ADD,
                                               int M, int N, int K) {
    __shared__ __align__(16) bf16 sA[128 * 32];
    __shared__ __align__(16) bf16 sB[128 * 32];
    __shared__ __align__(16) bf16 tbuf[EPI == 3 ? 4 * 64 * 72 : 4];

    const int wave = threadIdx.x >> 6;
    const int lane = threadIdx.x & 63;
    const int quad = lane >> 4;
    const int l16  = lane & 15;
    const int wm   = wave >> 1;
    const int wn   = wave & 1;

    const int m0 = blockIdx.y * 128;
    const int n0 = blockIdx.x * 128;

    // staging: wave w covers rows w*32 .. w*32+31 of each 128x32 tile
    const int srow = wave * 32 + (lane >> 2);
    const int scol = (lane & 3) * 8;
    const bf16* gA0 = A + (size_t)(m0 + srow) * K + scol;
    const bf16* gA1 = A + (size_t)(m0 + srow + 16) * K + scol;
    const bf16* gB0 = W + (size_t)(n0 + srow) * K + scol;
    const bf16* gB1 = W + (size_t)(n0 + srow + 16) * K + scol;
    bf16* lA0 = &sA[(wave * 32) * 32];
    bf16* lA1 = &sA[(wave * 32 + 16) * 32];
    bf16* lB0 = &sB[(wave * 32) * 32];
    bf16* lB1 = &sB[(wave * 32 + 16) * 32];

    f32x4 acc[4][4] = {};

    for (int k0 = 0; k0 < K; k0 += 32) {
        load16_lds(gA0 + k0, lA0);
        load16_lds(gA1 + k0, lA1);
        load16_lds(gB0 + k0, lB0);
        load16_lds(gB1 + k0, lB1);
        __syncthreads();   // drains vmcnt(0): tiles resident

        bf16x8 af[4], bfr[4];
#pragma unroll
        for (int s = 0; s < 4; ++s)
            af[s] = *reinterpret_cast<const bf16x8*>(&sA[(wm * 64 + s * 16 + l16) * 32 + quad * 8]);
#pragma unroll
        for (int t = 0; t < 4; ++t)
            bfr[t] = *reinterpret_cast<const bf16x8*>(&sB[(wn * 64 + t * 16 + l16) * 32 + quad * 8]);
#pragma unroll
        for (int s = 0; s < 4; ++s)
#pragma unroll
            for (int t = 0; t < 4; ++t)
                acc[s][t] = __builtin_amdgcn_mfma_f32_16x16x32_bf16(af[s], bfr[t], acc[s][t], 0, 0, 0);
        __syncthreads();   // before next overwrite
    }

    if constexpr (EPI == 3) {
        // per-wave transpose through LDS (64x64, stride 72 -> 2-way banks, free)
        bf16* tw = &tbuf[wave * 64 * 72];
#pragma unroll
        for (int s = 0; s < 4; ++s)
#pragma unroll
            for (int t = 0; t < 4; ++t)
#pragma unroll
                for (int r = 0; r < 4; ++r)
                    tw[(t * 16 + l16) * 72 + s * 16 + quad * 4 + r] = (bf16)acc[s][t][r];
        // same-wave readback (lgkmcnt handled by compiler), coalesced store along S
#pragma unroll
        for (int i = 0; i < 8; ++i) {
            const int flat = i * 64 + lane;
            const int nl = flat >> 3;        // 0..63 col within wave tile
            const int mc = flat & 7;         // 8-elem chunk along m
            bf16x8 v = *reinterpret_cast<const bf16x8*>(&tw[nl * 72 + mc * 8]);
            const int n_glob = n0 + wn * 64 + nl;
            const int m_glob = m0 + wm * 64 + mc * 8;
            const int bb = m_glob >> 11, sp = m_glob & (SEQ - 1);
            const int hh = n_glob >> 6,  dh = n_glob & 63;
            const size_t tidx = (((size_t)(bb * N_HEADS + hh) * D_HEAD + dh) << 11) + sp;
            *reinterpret_cast<bf16x8*>(&((bf16*)C)[tidx]) = v;
        }
    } else {
        const int n_base = n0 + wn * 64;
#pragma unroll
        for (int s = 0; s < 4; ++s) {
            const int mbase = m0 + wm * 64 + s * 16 + quad * 4;
#pragma unroll
            for (int t = 0; t < 4; ++t) {
                const int n = n_base + t * 16 + l16;
#pragma unroll
                for (int r = 0; r < 4; ++r) {
                    float v = acc[s][t][r];
                    if (EPI == 1) v = gelu_f(v);
                    const size_t idx = (size_t)(mbase + r) * N + n;
                    if (EPI == 2) v += ADD[idx];
                    C[idx] = (OutT)v;
                }
            }
        }
    }
}

// ---------------- Flash attention (causal), MFMA 16x16x32, work-balanced ----------------
__global__ __launch_bounds__(256) void flash_attn_kernel(const bf16* __restrict__ q,
                                                         const bf16* __restrict__ k,
                                                         const bf16* __restrict__ vt,
                                                         bf16* __restrict__ o) {
    const int pairIdx = blockIdx.x;        // 0..15
    const int bh    = blockIdx.y;          // 0..63
    const int b     = bh >> 4;
    const int h     = bh & 15;
    const int wave  = threadIdx.x >> 6;
    const int lane  = threadIdx.x & 63;
    const int quad  = lane >> 4;
    const int l16   = lane & 15;

    __shared__ bf16 pbuf[4][16][68];

    const bf16* kbase = k + (size_t)(b * SEQ) * D_MODEL + h * D_HEAD;
    const bf16* vbase = vt + ((size_t)(bh * D_HEAD) << 11);   // [dh][S]

    for (int half = 0; half < 2; ++half) {
        const int qtile = (half == 0) ? pairIdx : (SEQ / 64 - 1) - pairIdx;
        const int q0 = qtile * 64 + wave * 16;
        const size_t qrow = (size_t)(b * SEQ + q0 + l16) * D_MODEL + h * D_HEAD;
        bf16x8 qf0 = *reinterpret_cast<const bf16x8*>(q + qrow + quad * 8);
        bf16x8 qf1 = *reinterpret_cast<const bf16x8*>(q + qrow + 32 + quad * 8);

        f32x4 o_acc[4] = {(f32x4)(0.f), (f32x4)(0.f), (f32x4)(0.f), (f32x4)(0.f)};
        float m_r[4] = {-1e30f, -1e30f, -1e30f, -1e30f};
        float l_r[4] = {0.f, 0.f, 0.f, 0.f};

        for (int jt = 0; jt <= qtile; ++jt) {
            const int j0 = jt * 64;
            f32x4 s_acc[4] = {(f32x4)(0.f), (f32x4)(0.f), (f32x4)(0.f), (f32x4)(0.f)};
#pragma unroll
            for (int nb = 0; nb < 4; ++nb) {
                const bf16* kr = kbase + (size_t)(j0 + nb * 16 + l16) * D_MODEL;
                bf16x8 kf0 = *reinterpret_cast<const bf16x8*>(kr + quad * 8);
                bf16x8 kf1 = *reinterpret_cast<const bf16x8*>(kr + 32 + quad * 8);
                s_acc[nb] = __builtin_amdgcn_mfma_f32_16x16x32_bf16(qf0, kf0, s_acc[nb], 0, 0, 0);
                s_acc[nb] = __builtin_amdgcn_mfma_f32_16x16x32_bf16(qf1, kf1, s_acc[nb], 0, 0, 0);
            }
            const bool diag = (jt == qtile);
            float sv[4][4];
#pragma unroll
            for (int nb = 0; nb < 4; ++nb) {
                const int key = j0 + nb * 16 + l16;
#pragma unroll
                for (int r = 0; r < 4; ++r) {
                    float s = s_acc[nb][r] * 0.125f;
                    if (diag && key > q0 + quad * 4 + r) s = -1e30f;
                    sv[nb][r] = s;
                }
            }
#pragma unroll
            for (int r = 0; r < 4; ++r) {
                float mx = fmaxf(fmaxf(sv[0][r], sv[1][r]), fmaxf(sv[2][r], sv[3][r]));
#pragma unroll
                for (int off = 1; off < 16; off <<= 1) mx = fmaxf(mx, __shfl_xor(mx, off, 64));
                const float mn = fmaxf(m_r[r], mx);
                const float alpha = __expf(m_r[r] - mn);
                m_r[r] = mn;
                float rs = 0.f;
#pragma unroll
                for (int nb = 0; nb < 4; ++nb) {
                    float p = __expf(sv[nb][r] - mn);
                    rs += p;
                    pbuf[wave][quad * 4 + r][nb * 16 + l16] = (bf16)p;
                }
#pragma unroll
                for (int off = 1; off < 16; off <<= 1) rs += __shfl_xor(rs, off, 64);
                l_r[r] = l_r[r] * alpha + rs;
#pragma unroll
                for (int nb = 0; nb < 4; ++nb) o_acc[nb][r] *= alpha;
            }
            bf16x8 pf0 = *reinterpret_cast<const bf16x8*>(&pbuf[wave][l16][quad * 8]);
            bf16x8 pf1 = *reinterpret_cast<const bf16x8*>(&pbuf[wave][l16][32 + quad * 8]);
#pragma unroll
            for (int nb = 0; nb < 4; ++nb) {
                const bf16* vr = vbase + (((size_t)(nb * 16 + l16)) << 11) + j0;
                bf16x8 vf0 = *reinterpret_cast<const bf16x8*>(vr + quad * 8);
                bf16x8 vf1 = *reinterpret_cast<const bf16x8*>(vr + 32 + quad * 8);
                o_acc[nb] = __builtin_amdgcn_mfma_f32_16x16x32_bf16(pf0, vf0, o_acc[nb], 0, 0, 0);
                o_acc[nb] = __builtin_amdgcn_mfma_f32_16x16x32_bf16(pf1, vf1, o_acc[nb], 0, 0, 0);
            }
        }
#pragma unroll
        for (int nb = 0; nb < 4; ++nb) {
#pragma unroll
            for (int r = 0; r < 4; ++r) {
                const int qrow_g = q0 + quad * 4 + r;
                o[(size_t)(b * SEQ + qrow_g) * D_MODEL + h * D_HEAD + nb * 16 + l16] =
                    (bf16)(o_acc[nb][r] / l_r[r]);
            }
        }
    }
}

// ---------------- launch ----------------
// fp32 I/O. resid lives in d_out (read-modify-write in final FC2 is per-element safe).
// Workspace (88 MB, lifetime-aliased):
//   [0,24 MB)  : bf16 weights wq|wk|wv|wo|fc1|fc2
//   [24,40 MB) : n1 -> attn               (slotA)
//   [40,72 MB) : q | k                    (slotB; dead after wo-GEMM)
//   [72,88 MB) : vT -> n2
//   MLP: hid = [24,56 MB) (slotA+slotB first half; 4096-row chunks x2)
extern "C" void kernel_launch(void* const* d_in, const int* in_sizes, int n_in,
                              void* d_out, int out_size, void* d_ws, size_t ws_size,
                              hipStream_t stream) {
    const float* x      = (const float*)d_in[0];
    const float* gamma1 = (const float*)d_in[1];
    const float* beta1  = (const float*)d_in[2];
    const float* wq     = (const float*)d_in[3];
    const float* wk     = (const float*)d_in[4];
    const float* wv     = (const float*)d_in[5];
    const float* wo     = (const float*)d_in[6];
    const float* gamma2 = (const float*)d_in[7];
    const float* beta2  = (const float*)d_in[8];
    const float* fc1    = (const float*)d_in[9];
    const float* fc2    = (const float*)d_in[10];
    float* out = (float*)d_out;

    const size_t WSMALL = (size_t)N_HEADS * D_HEAD * D_MODEL;  // 1,048,576
    const size_t WFF    = (size_t)D_FF * D_MODEL;              // 4,194,304
    const size_t RD     = (size_t)ROWS * D_MODEL;              // 8,388,608

    char* wsb = (char*)d_ws;
    bf16* wq_b  = (bf16*)(wsb);
    bf16* wk_b  = wq_b + WSMALL;
    bf16* wv_b  = wk_b + WSMALL;
    bf16* wo_b  = wv_b + WSMALL;
    bf16* fc1_b = wo_b + WSMALL;
    bf16* fc2_b = fc1_b + WFF;            // ends at 24 MB
    bf16* slotA = fc2_b + WFF;            // 16 MB: n1 -> attn; MLP: hid starts here
    bf16* qb    = slotA + RD;             // 32 MB: q|k
    bf16* kb    = qb + RD;
    bf16* vtb   = kb + RD;                // 16 MB: vT -> n2
    bf16* n2    = vtb;

    bf16* n1    = slotA;
    bf16* attnb = slotA;
    bf16* hid   = slotA;                  // 32 MB when MLP runs (q|k dead)
    float* resid = out;                   // resid lives in d_out

    f2b_kernel<<<1024, 256, 0, stream>>>(wq,  wq_b,  (int)WSMALL);
    f2b_kernel<<<1024, 256, 0, stream>>>(wk,  wk_b,  (int)WSMALL);
    f2b_kernel<<<1024, 256, 0, stream>>>(wv,  wv_b,  (int)WSMALL);
    f2b_kernel<<<1024, 256, 0, stream>>>(wo,  wo_b,  (int)WSMALL);
    f2b_kernel<<<1024, 256, 0, stream>>>(fc1, fc1_b, (int)WFF);
    f2b_kernel<<<1024, 256, 0, stream>>>(fc2, fc2_b, (int)WFF);

    // LN1
    ln_kernel<<<ROWS, 256, 0, stream>>>(x, gamma1, beta1, n1);
    // projections (128-tile m97-style GEMM)
    gemm128<0, bf16><<<dim3(D_MODEL / 128, ROWS / 128), 256, 0, stream>>>(n1, wq_b, qb, nullptr, ROWS, D_MODEL, D_MODEL);
    gemm128<0, bf16><<<dim3(D_MODEL / 128, ROWS / 128), 256, 0, stream>>>(n1, wk_b, kb, nullptr, ROWS, D_MODEL, D_MODEL);
    gemm128<3, bf16><<<dim3(D_MODEL / 128, ROWS / 128), 256, 0, stream>>>(n1, wv_b, vtb, nullptr, ROWS, D_MODEL, D_MODEL);
    // flash attention
    flash_attn_kernel<<<dim3(SEQ / 128, BATCH * N_HEADS), 256, 0, stream>>>(qb, kb, vtb, attnb);
    // resid(d_out) = x + attn @ wo^T
    gemm128<2, float><<<dim3(D_MODEL / 128, ROWS / 128), 256, 0, stream>>>(attnb, wo_b, resid, x, ROWS, D_MODEL, D_MODEL);
    // LN2: resid -> n2
    ln_kernel<<<ROWS, 256, 0, stream>>>(resid, gamma2, beta2, n2);

    // MLP in 2 row-chunks of 4096; hid chunk = 4096x4096 bf16 = 32 MB
    const int CHUNK = 4096;
    for (int c = 0; c < ROWS / CHUNK; ++c) {
        const bf16*  n2c    = n2    + (size_t)c * CHUNK * D_MODEL;
        const float* residc = resid + (size_t)c * CHUNK * D_MODEL;
        float*       outc   = out   + (size_t)c * CHUNK * D_MODEL;
        gemm128<1, bf16><<<dim3(D_FF / 128, CHUNK / 128), 256, 0, stream>>>(n2c, fc1_b, hid, nullptr, CHUNK, D_FF, D_MODEL);
        gemm128<2, float><<<dim3(D_MODEL / 128, CHUNK / 128), 256, 0, stream>>>(hid, fc2_b, outc, residc, CHUNK, D_MODEL, D_FF);
    }
}

// Round 7
// 767.475 us; speedup vs baseline: 14.3005x; 1.2016x over previous
//
#include <hip/hip_runtime.h>
#include <hip/hip_bf16.h>

#define D_MODEL 1024
#define N_HEADS 16
#define D_HEAD  64
#define D_FF    4096
#define BATCH   4
#define SEQ     2048
#define ROWS    (BATCH*SEQ)   // 8192
#define LN_EPS  1e-5f

typedef __bf16 bf16;
typedef __bf16 bf16x8 __attribute__((ext_vector_type(8)));
typedef float  f32x4  __attribute__((ext_vector_type(4)));

// ---- async global->LDS 16B copy: dst is WAVE-UNIFORM base, HW adds lane*16B ----
__device__ __forceinline__ void load16_lds(const bf16* g, bf16* l) {
#if defined(__has_builtin) && __has_builtin(__builtin_amdgcn_global_load_lds)
    __builtin_amdgcn_global_load_lds(
        (const __attribute__((address_space(1))) unsigned int*)g,
        (__attribute__((address_space(3))) unsigned int*)l,
        16, 0, 0);
#else
    const int lane = threadIdx.x & 63;
    ((bf16x8*)l)[lane] = *(const bf16x8*)g;
#endif
}

// ---------------- fp32 -> bf16 converts (batched: 4 equal-size, 2 equal-size) ----------------
__global__ __launch_bounds__(256) void f2b4_kernel(const float* a, const float* b,
                                                   const float* c, const float* d,
                                                   bf16* oa, bf16* ob, bf16* oc, bf16* od,
                                                   int n) {
    const float* srcs[4] = {a, b, c, d};
    bf16* dsts[4] = {oa, ob, oc, od};
    const float* s = srcs[blockIdx.y];
    bf16* dst = dsts[blockIdx.y];
    int i = blockIdx.x * 256 + threadIdx.x;
    int stride = gridDim.x * 256;
    for (; i < n; i += stride) dst[i] = (bf16)s[i];
}
__global__ __launch_bounds__(256) void f2b2_kernel(const float* a, const float* b,
                                                   bf16* oa, bf16* ob, int n) {
    const float* s = blockIdx.y ? b : a;
    bf16* dst = blockIdx.y ? ob : oa;
    int i = blockIdx.x * 256 + threadIdx.x;
    int stride = gridDim.x * 256;
    for (; i < n; i += stride) dst[i] = (bf16)s[i];
}

// ---------------- LayerNorm: fp32 in -> bf16 out, one block per row ----------------
__global__ __launch_bounds__(256) void ln_kernel(const float* __restrict__ x,
                                                 const float* __restrict__ gamma,
                                                 const float* __restrict__ beta,
                                                 bf16* __restrict__ out) {
    const int row = blockIdx.x;
    const int tid = threadIdx.x;
    const float* xr = x + (size_t)row * D_MODEL;

    float vals[4];
    float s = 0.f, ss = 0.f;
#pragma unroll
    for (int t = 0; t < 4; ++t) {
        float v = xr[tid + t * 256];
        vals[t] = v;
        s += v;
        ss += v * v;
    }
#pragma unroll
    for (int off = 32; off > 0; off >>= 1) {
        s  += __shfl_xor(s, off, 64);
        ss += __shfl_xor(ss, off, 64);
    }
    __shared__ float sbuf[4], ssbuf[4];
    const int wave = tid >> 6;
    if ((tid & 63) == 0) { sbuf[wave] = s; ssbuf[wave] = ss; }
    __syncthreads();
    s  = sbuf[0] + sbuf[1] + sbuf[2] + sbuf[3];
    ss = ssbuf[0] + ssbuf[1] + ssbuf[2] + ssbuf[3];

    const float mean = s * (1.f / D_MODEL);
    const float var  = ss * (1.f / D_MODEL) - mean * mean;
    const float inv  = rsqrtf(var + LN_EPS);

    bf16* orow = out + (size_t)row * D_MODEL;
#pragma unroll
    for (int t = 0; t < 4; ++t) {
        int c = tid + t * 256;
        orow[c] = (bf16)(gamma[c] * ((vals[t] - mean) * inv) + beta[c]);
    }
}

// ---------------- GELU (tanh approx, matches reference) ----------------
__device__ __forceinline__ float gelu_f(float x) {
    float c = x * x * x;
    return 0.5f * x * (1.f + tanhf(0.7978845608f * (x + 0.044715f * c)));
}

// ---------------- GEMM m97-style: C[M,N] = A[M,K] @ W[N,K]^T (+epilogue) ----------------
// 256 threads = 4 waves; tile 128M x TN(64|128)N; BK=32; global_load_lds width-16 staging.
// TN=128: waves 2x2, each 64x64 (4x4 MFMA). TN=64: waves 4x1, each 32x64 (2x4 MFMA).
// EPI: 0 = plain store, 1 = gelu, 2 = v += ADD[idx] fp32 (C may alias ADD),
//      3 = store transposed [B,H,dh,S] (V), coalesced along S (TN=128 only).
template <int EPI, int TN, typename OutT>
__global__ __launch_bounds__(256) void gemm_mt(const bf16* __restrict__ A,
                                               const bf16* __restrict__ W,
                                               OutT* C,
                                               const float* ADD,
                                               int M, int N, int K) {
    constexpr int WN = TN / 64;          // waves along N
    constexpr int WM = 4 / WN;           // waves along M
    constexpr int SM = (128 / WM) / 16;  // M-subtiles per wave

    __shared__ __align__(16) bf16 sA[128 * 32];
    __shared__ __align__(16) bf16 sB[TN * 32];
    __shared__ __align__(16) bf16 tbuf[EPI == 3 ? 4 * 64 * 72 : 4];

    const int wave = threadIdx.x >> 6;
    const int lane = threadIdx.x & 63;
    const int quad = lane >> 4;
    const int l16  = lane & 15;
    const int wm   = wave / WN;
    const int wn   = wave % WN;

    const int m0 = blockIdx.y * 128;
    const int n0 = blockIdx.x * TN;

    const int srow = lane >> 2;          // 0..15
    const int scol = (lane & 3) * 8;
    const bf16* gA0 = A + (size_t)(m0 + wave * 32 + srow) * K + scol;
    const bf16* gA1 = gA0 + (size_t)16 * K;
    bf16* lA0 = &sA[(wave * 32) * 32];
    bf16* lA1 = &sA[(wave * 32 + 16) * 32];
    const bf16* gB0 = W + (size_t)(n0 + wave * (TN / 4) + srow) * K + scol;
    const bf16* gB1 = gB0 + (size_t)16 * K;
    bf16* lB0 = &sB[(wave * (TN / 4)) * 32];
    bf16* lB1 = &sB[(wave * (TN / 4) + 16) * 32];

    f32x4 acc[SM][4] = {};

    for (int k0 = 0; k0 < K; k0 += 32) {
        load16_lds(gA0 + k0, lA0);
        load16_lds(gA1 + k0, lA1);
        load16_lds(gB0 + k0, lB0);
        if constexpr (TN == 128) load16_lds(gB1 + k0, lB1);
        __syncthreads();

        bf16x8 af[SM], bfr[4];
#pragma unroll
        for (int s = 0; s < SM; ++s)
            af[s] = *reinterpret_cast<const bf16x8*>(&sA[(wm * (128 / WM) + s * 16 + l16) * 32 + quad * 8]);
#pragma unroll
        for (int t = 0; t < 4; ++t)
            bfr[t] = *reinterpret_cast<const bf16x8*>(&sB[(wn * 64 + t * 16 + l16) * 32 + quad * 8]);
#pragma unroll
        for (int s = 0; s < SM; ++s)
#pragma unroll
            for (int t = 0; t < 4; ++t)
                acc[s][t] = __builtin_amdgcn_mfma_f32_16x16x32_bf16(af[s], bfr[t], acc[s][t], 0, 0, 0);
        __syncthreads();
    }

    if constexpr (EPI == 3) {
        // per-wave transpose through LDS (64x64, stride 72), coalesced store along S
        bf16* tw = &tbuf[wave * 64 * 72];
#pragma unroll
        for (int s = 0; s < SM; ++s)
#pragma unroll
            for (int t = 0; t < 4; ++t)
#pragma unroll
                for (int r = 0; r < 4; ++r)
                    tw[(t * 16 + l16) * 72 + s * 16 + quad * 4 + r] = (bf16)acc[s][t][r];
#pragma unroll
        for (int i = 0; i < 8; ++i) {
            const int flat = i * 64 + lane;
            const int nl = flat >> 3;
            const int mc = flat & 7;
            bf16x8 v = *reinterpret_cast<const bf16x8*>(&tw[nl * 72 + mc * 8]);
            const int n_glob = n0 + wn * 64 + nl;
            const int m_glob = m0 + wm * 64 + mc * 8;
            const int bb = m_glob >> 11, sp = m_glob & (SEQ - 1);
            const int hh = n_glob >> 6,  dh = n_glob & 63;
            const size_t tidx = (((size_t)(bb * N_HEADS + hh) * D_HEAD + dh) << 11) + sp;
            *reinterpret_cast<bf16x8*>(&((bf16*)C)[tidx]) = v;
        }
    } else {
#pragma unroll
        for (int s = 0; s < SM; ++s) {
            const int mbase = m0 + wm * (128 / WM) + s * 16 + quad * 4;
#pragma unroll
            for (int t = 0; t < 4; ++t) {
                const int n = n0 + wn * 64 + t * 16 + l16;
#pragma unroll
                for (int r = 0; r < 4; ++r) {
                    float v = acc[s][t][r];
                    if (EPI == 1) v = gelu_f(v);
                    const size_t idx = (size_t)(mbase + r) * N + n;
                    if (EPI == 2) v += ADD[idx];
                    C[idx] = (OutT)v;
                }
            }
        }
    }
}

// ---------------- Flash attention (causal), latency-optimized ----------------
// Grid (16, B*H); block i does qtiles {i, 31-i} (uniform 33 iters). 4 waves x 16 q-rows.
// K-register prefetch; V hoisted; quad-shared max (exact); l via ones-MFMA.
__global__ __launch_bounds__(256) void flash_attn_kernel(const bf16* __restrict__ q,
                                                         const bf16* __restrict__ k,
                                                         const bf16* __restrict__ vt,
                                                         bf16* __restrict__ o) {
    const int pairIdx = blockIdx.x;        // 0..15
    const int bh    = blockIdx.y;          // 0..63
    const int b     = bh >> 4;
    const int h     = bh & 15;
    const int wave  = threadIdx.x >> 6;
    const int lane  = threadIdx.x & 63;
    const int quad  = lane >> 4;
    const int l16   = lane & 15;

    __shared__ bf16 pbuf[4][16][68];

    const bf16* kbase = k + (size_t)(b * SEQ) * D_MODEL + h * D_HEAD;
    const bf16* vbase = vt + ((size_t)(bh * D_HEAD) << 11);   // [dh][S]

    bf16x8 ones;
#pragma unroll
    for (int i = 0; i < 8; ++i) ones[i] = (bf16)1.0f;

    for (int half = 0; half < 2; ++half) {
        const int qtile = (half == 0) ? pairIdx : (SEQ / 64 - 1) - pairIdx;
        const int q0 = qtile * 64 + wave * 16;
        const size_t qrow = (size_t)(b * SEQ + q0 + l16) * D_MODEL + h * D_HEAD;
        bf16x8 qf0 = *reinterpret_cast<const bf16x8*>(q + qrow + quad * 8);
        bf16x8 qf1 = *reinterpret_cast<const bf16x8*>(q + qrow + 32 + quad * 8);

        f32x4 o_acc[4] = {(f32x4)(0.f), (f32x4)(0.f), (f32x4)(0.f), (f32x4)(0.f)};
        float m_q = -1e30f;                      // shared max for the quad's 4 rows (exact)
        float l_r[4] = {0.f, 0.f, 0.f, 0.f};

        // preload K tile 0
        bf16x8 kf0[4], kf1[4];
#pragma unroll
        for (int nb = 0; nb < 4; ++nb) {
            const bf16* kr = kbase + (size_t)(nb * 16 + l16) * D_MODEL;
            kf0[nb] = *reinterpret_cast<const bf16x8*>(kr + quad * 8);
            kf1[nb] = *reinterpret_cast<const bf16x8*>(kr + 32 + quad * 8);
        }

        for (int jt = 0; jt <= qtile; ++jt) {
            const int j0 = jt * 64;
            // V loads for this tile (latency hidden behind QK + softmax)
            bf16x8 vf0[4], vf1[4];
#pragma unroll
            for (int nb = 0; nb < 4; ++nb) {
                const bf16* vr = vbase + (((size_t)(nb * 16 + l16)) << 11) + j0;
                vf0[nb] = *reinterpret_cast<const bf16x8*>(vr + quad * 8);
                vf1[nb] = *reinterpret_cast<const bf16x8*>(vr + 32 + quad * 8);
            }
            // QK^T
            f32x4 s_acc[4] = {(f32x4)(0.f), (f32x4)(0.f), (f32x4)(0.f), (f32x4)(0.f)};
#pragma unroll
            for (int nb = 0; nb < 4; ++nb) {
                s_acc[nb] = __builtin_amdgcn_mfma_f32_16x16x32_bf16(qf0, kf0[nb], s_acc[nb], 0, 0, 0);
                s_acc[nb] = __builtin_amdgcn_mfma_f32_16x16x32_bf16(qf1, kf1[nb], s_acc[nb], 0, 0, 0);
            }
            // prefetch next K tile (hidden behind softmax + PV)
            if (jt < qtile) {
                const int j0n = j0 + 64;
#pragma unroll
                for (int nb = 0; nb < 4; ++nb) {
                    const bf16* kr = kbase + (size_t)(j0n + nb * 16 + l16) * D_MODEL;
                    kf0[nb] = *reinterpret_cast<const bf16x8*>(kr + quad * 8);
                    kf1[nb] = *reinterpret_cast<const bf16x8*>(kr + 32 + quad * 8);
                }
            }
            // scale + mask + local max over the quad's 4 rows x 64 keys
            const bool diag = (jt == qtile);
            float sv[4][4];
            float mx = -1e30f;
#pragma unroll
            for (int nb = 0; nb < 4; ++nb) {
                const int key = j0 + nb * 16 + l16;
#pragma unroll
                for (int r = 0; r < 4; ++r) {
                    float s = s_acc[nb][r] * 0.125f;
                    if (diag && key > q0 + quad * 4 + r) s = -1e30f;
                    sv[nb][r] = s;
                    mx = fmaxf(mx, s);
                }
            }
#pragma unroll
            for (int off = 1; off < 16; off <<= 1) mx = fmaxf(mx, __shfl_xor(mx, off, 64));
            const float mn = fmaxf(m_q, mx);
            const float alpha = __expf(m_q - mn);
            m_q = mn;
            // P = exp(S - m), staged to LDS (C->A layout transform)
#pragma unroll
            for (int nb = 0; nb < 4; ++nb)
#pragma unroll
                for (int r = 0; r < 4; ++r)
                    pbuf[wave][quad * 4 + r][nb * 16 + l16] = (bf16)__expf(sv[nb][r] - mn);
            // rescale
#pragma unroll
            for (int r = 0; r < 4; ++r) l_r[r] *= alpha;
#pragma unroll
            for (int nb = 0; nb < 4; ++nb) o_acc[nb] *= alpha;
            // read back P (same-wave; compiler inserts lgkmcnt)
            bf16x8 pf0 = *reinterpret_cast<const bf16x8*>(&pbuf[wave][l16][quad * 8]);
            bf16x8 pf1 = *reinterpret_cast<const bf16x8*>(&pbuf[wave][l16][32 + quad * 8]);
            // l += P @ ones  (row sums via MFMA, no shuffles)
            f32x4 lt = (f32x4)(0.f);
            lt = __builtin_amdgcn_mfma_f32_16x16x32_bf16(pf0, ones, lt, 0, 0, 0);
            lt = __builtin_amdgcn_mfma_f32_16x16x32_bf16(pf1, ones, lt, 0, 0, 0);
#pragma unroll
            for (int r = 0; r < 4; ++r) l_r[r] += lt[r];
            // O += P @ V
#pragma unroll
            for (int nb = 0; nb < 4; ++nb) {
                o_acc[nb] = __builtin_amdgcn_mfma_f32_16x16x32_bf16(pf0, vf0[nb], o_acc[nb], 0, 0, 0);
                o_acc[nb] = __builtin_amdgcn_mfma_f32_16x16x32_bf16(pf1, vf1[nb], o_acc[nb], 0, 0, 0);
            }
        }
        // epilogue
#pragma unroll
        for (int nb = 0; nb < 4; ++nb) {
#pragma unroll
            for (int r = 0; r < 4; ++r) {
                const int qrow_g = q0 + quad * 4 + r;
                o[(size_t)(b * SEQ + qrow_g) * D_MODEL + h * D_HEAD + nb * 16 + l16] =
                    (bf16)(o_acc[nb][r] / l_r[r]);
            }
        }
    }
}

// ---------------- launch ----------------
// fp32 I/O. resid lives in d_out. Workspace (lifetime-aliased):
//   [0,24)   MB : bf16 weights wq|wk|wv|wo|fc1|fc2
//   [24,40)  MB : n1 -> attn -> hid(start)
//   [40,72)  MB : q | k   (dead after flash/wo)
//   [72,88)  MB : vT  (dead after flash)
//   MLP: if ws >= 104 MB: hid = [24,88) full 64 MB, n2 = [88,104); else 2-chunk, n2 = [72,88).
extern "C" void kernel_launch(void* const* d_in, const int* in_sizes, int n_in,
                              void* d_out, int out_size, void* d_ws, size_t ws_size,
                              hipStream_t stream) {
    const float* x      = (const float*)d_in[0];
    const float* gamma1 = (const float*)d_in[1];
    const float* beta1  = (const float*)d_in[2];
    const float* wq     = (const float*)d_in[3];
    const float* wk     = (const float*)d_in[4];
    const float* wv     = (const float*)d_in[5];
    const float* wo     = (const float*)d_in[6];
    const float* gamma2 = (const float*)d_in[7];
    const float* beta2  = (const float*)d_in[8];
    const float* fc1    = (const float*)d_in[9];
    const float* fc2    = (const float*)d_in[10];
    float* out = (float*)d_out;

    const size_t WSMALL = (size_t)N_HEADS * D_HEAD * D_MODEL;  // 1,048,576
    const size_t WFF    = (size_t)D_FF * D_MODEL;              // 4,194,304
    const size_t RD     = (size_t)ROWS * D_MODEL;              // 8,388,608

    char* wsb = (char*)d_ws;
    bf16* wq_b  = (bf16*)(wsb);
    bf16* wk_b  = wq_b + WSMALL;
    bf16* wv_b  = wk_b + WSMALL;
    bf16* wo_b  = wv_b + WSMALL;
    bf16* fc1_b = wo_b + WSMALL;
    bf16* fc2_b = fc1_b + WFF;            // ends at 24 MB
    bf16* slotA = fc2_b + WFF;            // [24,40): n1 -> attn -> hid
    bf16* qb    = slotA + RD;             // [40,56)
    bf16* kb    = qb + RD;                // [56,72)
    bf16* vtb   = kb + RD;                // [72,88)

    bf16* n1    = slotA;
    bf16* attnb = slotA;
    bf16* hid   = slotA;
    float* resid = out;

    const size_t need_single = (size_t)(24 + 64 + 16) * 1024 * 1024;
    const bool single = ws_size >= need_single;
    bf16* n2 = single ? (bf16*)(wsb + (size_t)88 * 1024 * 1024) : vtb;

    // weight conversion fp32 -> bf16 (2 launches)
    f2b4_kernel<<<dim3(64, 4), 256, 0, stream>>>(wq, wk, wv, wo, wq_b, wk_b, wv_b, wo_b, (int)WSMALL);
    f2b2_kernel<<<dim3(256, 2), 256, 0, stream>>>(fc1, fc2, fc1_b, fc2_b, (int)WFF);

    // LN1
    ln_kernel<<<ROWS, 256, 0, stream>>>(x, gamma1, beta1, n1);
    // projections: TN=64 (1024 blocks) for Q,K; V uses TN=128 transpose path
    gemm_mt<0, 64, bf16><<<dim3(D_MODEL / 64, ROWS / 128), 256, 0, stream>>>(n1, wq_b, qb, nullptr, ROWS, D_MODEL, D_MODEL);
    gemm_mt<0, 64, bf16><<<dim3(D_MODEL / 64, ROWS / 128), 256, 0, stream>>>(n1, wk_b, kb, nullptr, ROWS, D_MODEL, D_MODEL);
    gemm_mt<3, 128, bf16><<<dim3(D_MODEL / 128, ROWS / 128), 256, 0, stream>>>(n1, wv_b, vtb, nullptr, ROWS, D_MODEL, D_MODEL);
    // flash attention
    flash_attn_kernel<<<dim3(SEQ / 128, BATCH * N_HEADS), 256, 0, stream>>>(qb, kb, vtb, attnb);
    // resid(d_out) = x + attn @ wo^T
    gemm_mt<2, 64, float><<<dim3(D_MODEL / 64, ROWS / 128), 256, 0, stream>>>(attnb, wo_b, resid, x, ROWS, D_MODEL, D_MODEL);
    // LN2
    ln_kernel<<<ROWS, 256, 0, stream>>>(resid, gamma2, beta2, n2);

    if (single) {
        gemm_mt<1, 128, bf16><<<dim3(D_FF / 128, ROWS / 128), 256, 0, stream>>>(n2, fc1_b, hid, nullptr, ROWS, D_FF, D_MODEL);
        gemm_mt<2, 64, float><<<dim3(D_MODEL / 64, ROWS / 128), 256, 0, stream>>>(hid, fc2_b, out, resid, ROWS, D_MODEL, D_FF);
    } else {
        const int CHUNK = 4096;   // hid chunk = 32 MB in [24,56)
        for (int c = 0; c < ROWS / CHUNK; ++c) {
            const bf16*  n2c    = n2    + (size_t)c * CHUNK * D_MODEL;
            const float* residc = resid + (size_t)c * CHUNK * D_MODEL;
            float*       outc   = out   + (size_t)c * CHUNK * D_MODEL;
            gemm_mt<1, 128, bf16><<<dim3(D_FF / 128, CHUNK / 128), 256, 0, stream>>>(n2c, fc1_b, hid, nullptr, CHUNK, D_FF, D_MODEL);
            gemm_mt<2, 64, float><<<dim3(D_MODEL / 64, CHUNK / 128), 256, 0, stream>>>(hid, fc2_b, outc, residc, CHUNK, D_MODEL, D_FF);
        }
    }
}

// Round 8
// 733.134 us; speedup vs baseline: 14.9704x; 1.0468x over previous
//
#include <hip/hip_runtime.h>
#include <hip/hip_bf16.h>

#define D_MODEL 1024
#define N_HEADS 16
#define D_HEAD  64
#define D_FF    4096
#define BATCH   4
#define SEQ     2048
#define ROWS    (BATCH*SEQ)   // 8192
#define LN_EPS  1e-5f

typedef __bf16 bf16;
typedef __bf16 bf16x8 __attribute__((ext_vector_type(8)));
typedef float  f32x4  __attribute__((ext_vector_type(4)));

// ---- async global->LDS 16B copy: dst is WAVE-UNIFORM base, HW adds lane*16B ----
__device__ __forceinline__ void load16_lds(const bf16* g, bf16* l) {
#if defined(__has_builtin) && __has_builtin(__builtin_amdgcn_global_load_lds)
    __builtin_amdgcn_global_load_lds(
        (const __attribute__((address_space(1))) unsigned int*)g,
        (__attribute__((address_space(3))) unsigned int*)l,
        16, 0, 0);
#else
    const int lane = threadIdx.x & 63;
    ((bf16x8*)l)[lane] = *(const bf16x8*)g;
#endif
}

// ---------------- fp32 -> bf16 converts (batched) ----------------
__global__ __launch_bounds__(256) void f2b4_kernel(const float* a, const float* b,
                                                   const float* c, const float* d,
                                                   bf16* oa, bf16* ob, bf16* oc, bf16* od,
                                                   int n) {
    const float* srcs[4] = {a, b, c, d};
    bf16* dsts[4] = {oa, ob, oc, od};
    const float* s = srcs[blockIdx.y];
    bf16* dst = dsts[blockIdx.y];
    int i = blockIdx.x * 256 + threadIdx.x;
    int stride = gridDim.x * 256;
    for (; i < n; i += stride) dst[i] = (bf16)s[i];
}
__global__ __launch_bounds__(256) void f2b2_kernel(const float* a, const float* b,
                                                   bf16* oa, bf16* ob, int n) {
    const float* s = blockIdx.y ? b : a;
    bf16* dst = blockIdx.y ? ob : oa;
    int i = blockIdx.x * 256 + threadIdx.x;
    int stride = gridDim.x * 256;
    for (; i < n; i += stride) dst[i] = (bf16)s[i];
}

// ---------------- LayerNorm: fp32 in -> bf16 out, one block per row ----------------
__global__ __launch_bounds__(256) void ln_kernel(const float* __restrict__ x,
                                                 const float* __restrict__ gamma,
                                                 const float* __restrict__ beta,
                                                 bf16* __restrict__ out) {
    const int row = blockIdx.x;
    const int tid = threadIdx.x;
    const float* xr = x + (size_t)row * D_MODEL;

    float vals[4];
    float s = 0.f, ss = 0.f;
#pragma unroll
    for (int t = 0; t < 4; ++t) {
        float v = xr[tid + t * 256];
        vals[t] = v;
        s += v;
        ss += v * v;
    }
#pragma unroll
    for (int off = 32; off > 0; off >>= 1) {
        s  += __shfl_xor(s, off, 64);
        ss += __shfl_xor(ss, off, 64);
    }
    __shared__ float sbuf[4], ssbuf[4];
    const int wave = tid >> 6;
    if ((tid & 63) == 0) { sbuf[wave] = s; ssbuf[wave] = ss; }
    __syncthreads();
    s  = sbuf[0] + sbuf[1] + sbuf[2] + sbuf[3];
    ss = ssbuf[0] + ssbuf[1] + ssbuf[2] + ssbuf[3];

    const float mean = s * (1.f / D_MODEL);
    const float var  = ss * (1.f / D_MODEL) - mean * mean;
    const float inv  = rsqrtf(var + LN_EPS);

    bf16* orow = out + (size_t)row * D_MODEL;
#pragma unroll
    for (int t = 0; t < 4; ++t) {
        int c = tid + t * 256;
        orow[c] = (bf16)(gamma[c] * ((vals[t] - mean) * inv) + beta[c]);
    }
}

// ---------------- GELU (tanh approx, matches reference) ----------------
__device__ __forceinline__ float gelu_f(float x) {
    float c = x * x * x;
    return 0.5f * x * (1.f + tanhf(0.7978845608f * (x + 0.044715f * c)));
}

// ---------------- GEMM m97-style: C[M,N] = A[M,K] @ W[N,K]^T (+epilogue) ----------------
// 256 threads = 4 waves; tile 128M x TN(64|128)N; BK=32; global_load_lds width-16 staging.
// EPI: 0 plain; 1 gelu; 2 v += ADD[idx] fp32 (C may alias ADD);
//      4 fused-QKV: cols [0,2048) -> C with row stride 2048 (q|k), cols [2048,3072)
//        -> VT transposed [B,H,dh,S] via per-wave LDS (TN=128 only).
template <int EPI, int TN, typename OutT>
__global__ __launch_bounds__(256) void gemm_mt(const bf16* __restrict__ A,
                                               const bf16* __restrict__ W,
                                               OutT* C,
                                               const float* ADD,
                                               bf16* VT,
                                               int M, int N, int K) {
    constexpr int WN = TN / 64;          // waves along N
    constexpr int WM = 4 / WN;           // waves along M
    constexpr int SM = (128 / WM) / 16;  // M-subtiles per wave

    __shared__ __align__(16) bf16 sA[128 * 32];
    __shared__ __align__(16) bf16 sB[TN * 32];
    __shared__ __align__(16) bf16 tbuf[EPI == 4 ? 4 * 64 * 72 : 4];

    const int wave = threadIdx.x >> 6;
    const int lane = threadIdx.x & 63;
    const int quad = lane >> 4;
    const int l16  = lane & 15;
    const int wm   = wave / WN;
    const int wn   = wave % WN;

    const int m0 = blockIdx.y * 128;
    const int n0 = blockIdx.x * TN;

    const int srow = lane >> 2;          // 0..15
    const int scol = (lane & 3) * 8;
    const bf16* gA0 = A + (size_t)(m0 + wave * 32 + srow) * K + scol;
    const bf16* gA1 = gA0 + (size_t)16 * K;
    bf16* lA0 = &sA[(wave * 32) * 32];
    bf16* lA1 = &sA[(wave * 32 + 16) * 32];
    const bf16* gB0 = W + (size_t)(n0 + wave * (TN / 4) + srow) * K + scol;
    const bf16* gB1 = gB0 + (size_t)16 * K;
    bf16* lB0 = &sB[(wave * (TN / 4)) * 32];
    bf16* lB1 = &sB[(wave * (TN / 4) + 16) * 32];

    f32x4 acc[SM][4] = {};

    for (int k0 = 0; k0 < K; k0 += 32) {
        load16_lds(gA0 + k0, lA0);
        load16_lds(gA1 + k0, lA1);
        load16_lds(gB0 + k0, lB0);
        if constexpr (TN == 128) load16_lds(gB1 + k0, lB1);
        __syncthreads();

        bf16x8 af[SM], bfr[4];
#pragma unroll
        for (int s = 0; s < SM; ++s)
            af[s] = *reinterpret_cast<const bf16x8*>(&sA[(wm * (128 / WM) + s * 16 + l16) * 32 + quad * 8]);
#pragma unroll
        for (int t = 0; t < 4; ++t)
            bfr[t] = *reinterpret_cast<const bf16x8*>(&sB[(wn * 64 + t * 16 + l16) * 32 + quad * 8]);
#pragma unroll
        for (int s = 0; s < SM; ++s)
#pragma unroll
            for (int t = 0; t < 4; ++t)
                acc[s][t] = __builtin_amdgcn_mfma_f32_16x16x32_bf16(af[s], bfr[t], acc[s][t], 0, 0, 0);
        __syncthreads();
    }

    if constexpr (EPI == 4) {
        if (n0 >= 2048) {
            // V columns: per-wave transpose through LDS (64x64, stride 72), store [B,H,dh,S]
            bf16* tw = &tbuf[wave * 64 * 72];
#pragma unroll
            for (int s = 0; s < SM; ++s)
#pragma unroll
                for (int t = 0; t < 4; ++t)
#pragma unroll
                    for (int r = 0; r < 4; ++r)
                        tw[(t * 16 + l16) * 72 + s * 16 + quad * 4 + r] = (bf16)acc[s][t][r];
#pragma unroll
            for (int i = 0; i < 8; ++i) {
                const int flat = i * 64 + lane;
                const int nl = flat >> 3;
                const int mc = flat & 7;
                bf16x8 v = *reinterpret_cast<const bf16x8*>(&tw[nl * 72 + mc * 8]);
                const int vcol = n0 - 2048 + wn * 64 + nl;
                const int m_glob = m0 + wm * 64 + mc * 8;
                const int bb = m_glob >> 11, sp = m_glob & (SEQ - 1);
                const int hh = vcol >> 6,  dh = vcol & 63;
                const size_t tidx = (((size_t)(bb * N_HEADS + hh) * D_HEAD + dh) << 11) + sp;
                *reinterpret_cast<bf16x8*>(&VT[tidx]) = v;
            }
        } else {
            // Q|K columns: row stride 2048
#pragma unroll
            for (int s = 0; s < SM; ++s) {
                const int mbase = m0 + wm * (128 / WM) + s * 16 + quad * 4;
#pragma unroll
                for (int t = 0; t < 4; ++t) {
                    const int n = n0 + wn * 64 + t * 16 + l16;
#pragma unroll
                    for (int r = 0; r < 4; ++r)
                        C[(size_t)(mbase + r) * 2048 + n] = (OutT)acc[s][t][r];
                }
            }
        }
    } else {
#pragma unroll
        for (int s = 0; s < SM; ++s) {
            const int mbase = m0 + wm * (128 / WM) + s * 16 + quad * 4;
#pragma unroll
            for (int t = 0; t < 4; ++t) {
                const int n = n0 + wn * 64 + t * 16 + l16;
#pragma unroll
                for (int r = 0; r < 4; ++r) {
                    float v = acc[s][t][r];
                    if (EPI == 1) v = gelu_f(v);
                    const size_t idx = (size_t)(mbase + r) * N + n;
                    if (EPI == 2) v += ADD[idx];
                    C[idx] = (OutT)v;
                }
            }
        }
    }
}

// ---------------- Flash attention (causal), 1-wave blocks, XCD-affine ----------------
// Grid: 4096 x 64 threads. id = bh%8 + 8*(pair + 64*(bh/8)) -> all 64 blocks of a
// head hit one XCD consecutively (K/V stay in its 4MB L2). Each block: two 16-row
// q-strips {pair, 127-pair} (uniform ~33 K-tiles). qk: [8192,2048] bf16 (q cols 0-1023,
// k cols 1024-2047). vt: [B,H,dh,S]. o: [B*S, D_MODEL].
__global__ __launch_bounds__(64) void flash_attn_kernel(const bf16* __restrict__ qk,
                                                        const bf16* __restrict__ vt,
                                                        bf16* __restrict__ o) {
    const int id   = blockIdx.x;
    const int bhl  = id & 7;
    const int rest = id >> 3;
    const int pair = rest & 63;
    const int bh   = (rest >> 6) * 8 + bhl;
    const int b    = bh >> 4;
    const int h    = bh & 15;
    const int lane = threadIdx.x;
    const int quad = lane >> 4;
    const int l16  = lane & 15;

    __shared__ bf16 pbuf[16][68];

    const bf16* kbase = qk + (size_t)(b * SEQ) * 2048 + 1024 + h * D_HEAD;
    const bf16* vbase = vt + ((size_t)(bh * D_HEAD) << 11);   // [dh][S]

    bf16x8 ones;
#pragma unroll
    for (int i = 0; i < 8; ++i) ones[i] = (bf16)1.0f;

    for (int half = 0; half < 2; ++half) {
        const int strip = (half == 0) ? pair : 127 - pair;
        const int q0 = strip * 16;
        const size_t qrow = (size_t)(b * SEQ + q0 + l16) * 2048 + h * D_HEAD;
        bf16x8 qf0 = *reinterpret_cast<const bf16x8*>(qk + qrow + quad * 8);
        bf16x8 qf1 = *reinterpret_cast<const bf16x8*>(qk + qrow + 32 + quad * 8);

        f32x4 o_acc[4] = {(f32x4)(0.f), (f32x4)(0.f), (f32x4)(0.f), (f32x4)(0.f)};
        float m_q = -1e30f;
        float l_r[4] = {0.f, 0.f, 0.f, 0.f};

        const int jtmax = q0 >> 6;
        // preload K tile 0
        bf16x8 kf0[4], kf1[4];
#pragma unroll
        for (int nb = 0; nb < 4; ++nb) {
            const bf16* kr = kbase + (size_t)(nb * 16 + l16) * 2048;
            kf0[nb] = *reinterpret_cast<const bf16x8*>(kr + quad * 8);
            kf1[nb] = *reinterpret_cast<const bf16x8*>(kr + 32 + quad * 8);
        }

        for (int jt = 0; jt <= jtmax; ++jt) {
            const int j0 = jt * 64;
            // V loads for this tile
            bf16x8 vf0[4], vf1[4];
#pragma unroll
            for (int nb = 0; nb < 4; ++nb) {
                const bf16* vr = vbase + (((size_t)(nb * 16 + l16)) << 11) + j0;
                vf0[nb] = *reinterpret_cast<const bf16x8*>(vr + quad * 8);
                vf1[nb] = *reinterpret_cast<const bf16x8*>(vr + 32 + quad * 8);
            }
            // QK^T
            f32x4 s_acc[4] = {(f32x4)(0.f), (f32x4)(0.f), (f32x4)(0.f), (f32x4)(0.f)};
#pragma unroll
            for (int nb = 0; nb < 4; ++nb) {
                s_acc[nb] = __builtin_amdgcn_mfma_f32_16x16x32_bf16(qf0, kf0[nb], s_acc[nb], 0, 0, 0);
                s_acc[nb] = __builtin_amdgcn_mfma_f32_16x16x32_bf16(qf1, kf1[nb], s_acc[nb], 0, 0, 0);
            }
            // prefetch next K tile
            if (jt < jtmax) {
                const int j0n = j0 + 64;
#pragma unroll
                for (int nb = 0; nb < 4; ++nb) {
                    const bf16* kr = kbase + (size_t)(j0n + nb * 16 + l16) * 2048;
                    kf0[nb] = *reinterpret_cast<const bf16x8*>(kr + quad * 8);
                    kf1[nb] = *reinterpret_cast<const bf16x8*>(kr + 32 + quad * 8);
                }
            }
            // scale + causal mask + quad-local max (exact: uniform shift per quad)
            const bool diag = (jt == jtmax);
            float sv[4][4];
            float mx = -1e30f;
#pragma unroll
            for (int nb = 0; nb < 4; ++nb) {
                const int key = j0 + nb * 16 + l16;
#pragma unroll
                for (int r = 0; r < 4; ++r) {
                    float s = s_acc[nb][r] * 0.125f;
                    if (diag && key > q0 + quad * 4 + r) s = -1e30f;
                    sv[nb][r] = s;
                    mx = fmaxf(mx, s);
                }
            }
#pragma unroll
            for (int off = 1; off < 16; off <<= 1) mx = fmaxf(mx, __shfl_xor(mx, off, 64));
            const float mn = fmaxf(m_q, mx);
            const float alpha = __expf(m_q - mn);
            m_q = mn;
            // P = exp(S - m) -> LDS (C->A layout transform)
#pragma unroll
            for (int nb = 0; nb < 4; ++nb)
#pragma unroll
                for (int r = 0; r < 4; ++r)
                    pbuf[quad * 4 + r][nb * 16 + l16] = (bf16)__expf(sv[nb][r] - mn);
#pragma unroll
            for (int r = 0; r < 4; ++r) l_r[r] *= alpha;
#pragma unroll
            for (int nb = 0; nb < 4; ++nb) o_acc[nb] *= alpha;
            bf16x8 pf0 = *reinterpret_cast<const bf16x8*>(&pbuf[l16][quad * 8]);
            bf16x8 pf1 = *reinterpret_cast<const bf16x8*>(&pbuf[l16][32 + quad * 8]);
            // l += P @ ones
            f32x4 lt = (f32x4)(0.f);
            lt = __builtin_amdgcn_mfma_f32_16x16x32_bf16(pf0, ones, lt, 0, 0, 0);
            lt = __builtin_amdgcn_mfma_f32_16x16x32_bf16(pf1, ones, lt, 0, 0, 0);
#pragma unroll
            for (int r = 0; r < 4; ++r) l_r[r] += lt[r];
            // O += P @ V
#pragma unroll
            for (int nb = 0; nb < 4; ++nb) {
                o_acc[nb] = __builtin_amdgcn_mfma_f32_16x16x32_bf16(pf0, vf0[nb], o_acc[nb], 0, 0, 0);
                o_acc[nb] = __builtin_amdgcn_mfma_f32_16x16x32_bf16(pf1, vf1[nb], o_acc[nb], 0, 0, 0);
            }
        }
        // epilogue
#pragma unroll
        for (int nb = 0; nb < 4; ++nb) {
#pragma unroll
            for (int r = 0; r < 4; ++r) {
                const int qrow_g = q0 + quad * 4 + r;
                o[(size_t)(b * SEQ + qrow_g) * D_MODEL + h * D_HEAD + nb * 16 + l16] =
                    (bf16)(o_acc[nb][r] / l_r[r]);
            }
        }
    }
}

// ---------------- launch ----------------
// fp32 I/O. resid lives in d_out. Workspace (lifetime-aliased):
//   [0,24)   MB : bf16 weights wq|wk|wv (=wqkv, contiguous) |wo|fc1|fc2
//   [24,40)  MB : n1 -> attn -> hid(start)
//   [40,72)  MB : qk [8192,2048] (dead after flash)
//   [72,88)  MB : vT (dead after flash)
//   MLP: if ws >= 104 MB: hid = [24,88), n2 = [88,104); else 2-chunk, n2 = [72,88).
extern "C" void kernel_launch(void* const* d_in, const int* in_sizes, int n_in,
                              void* d_out, int out_size, void* d_ws, size_t ws_size,
                              hipStream_t stream) {
    const float* x      = (const float*)d_in[0];
    const float* gamma1 = (const float*)d_in[1];
    const float* beta1  = (const float*)d_in[2];
    const float* wq     = (const float*)d_in[3];
    const float* wk     = (const float*)d_in[4];
    const float* wv     = (const float*)d_in[5];
    const float* wo     = (const float*)d_in[6];
    const float* gamma2 = (const float*)d_in[7];
    const float* beta2  = (const float*)d_in[8];
    const float* fc1    = (const float*)d_in[9];
    const float* fc2    = (const float*)d_in[10];
    float* out = (float*)d_out;

    const size_t WSMALL = (size_t)N_HEADS * D_HEAD * D_MODEL;  // 1,048,576
    const size_t WFF    = (size_t)D_FF * D_MODEL;              // 4,194,304
    const size_t RD     = (size_t)ROWS * D_MODEL;              // 8,388,608

    char* wsb = (char*)d_ws;
    bf16* wq_b  = (bf16*)(wsb);           // wq|wk|wv contiguous = wqkv [3072,1024]
    bf16* wk_b  = wq_b + WSMALL;
    bf16* wv_b  = wk_b + WSMALL;
    bf16* wo_b  = wv_b + WSMALL;
    bf16* fc1_b = wo_b + WSMALL;
    bf16* fc2_b = fc1_b + WFF;            // ends at 24 MB
    bf16* slotA = fc2_b + WFF;            // [24,40): n1 -> attn -> hid
    bf16* qkb   = slotA + RD;             // [40,72): q|k stride-2048
    bf16* vtb   = qkb + 2 * RD;           // [72,88)

    bf16* n1    = slotA;
    bf16* attnb = slotA;
    bf16* hid   = slotA;
    float* resid = out;

    const size_t need_single = (size_t)(24 + 64 + 16) * 1024 * 1024;
    const bool single = ws_size >= need_single;
    bf16* n2 = single ? (bf16*)(wsb + (size_t)88 * 1024 * 1024) : vtb;

    // weight conversion fp32 -> bf16
    f2b4_kernel<<<dim3(64, 4), 256, 0, stream>>>(wq, wk, wv, wo, wq_b, wk_b, wv_b, wo_b, (int)WSMALL);
    f2b2_kernel<<<dim3(256, 2), 256, 0, stream>>>(fc1, fc2, fc1_b, fc2_b, (int)WFF);

    // LN1
    ln_kernel<<<ROWS, 256, 0, stream>>>(x, gamma1, beta1, n1);
    // fused QKV: [8192,1024] @ wqkv[3072,1024]^T; q|k -> qkb (stride 2048), v -> vtb (transposed)
    gemm_mt<4, 128, bf16><<<dim3(3072 / 128, ROWS / 128), 256, 0, stream>>>(n1, wq_b, qkb, nullptr, vtb, ROWS, 3072, D_MODEL);
    // flash attention (1-wave blocks, XCD-affine)
    flash_attn_kernel<<<4096, 64, 0, stream>>>(qkb, vtb, attnb);
    // resid(d_out) = x + attn @ wo^T
    gemm_mt<2, 64, float><<<dim3(D_MODEL / 64, ROWS / 128), 256, 0, stream>>>(attnb, wo_b, resid, x, nullptr, ROWS, D_MODEL, D_MODEL);
    // LN2
    ln_kernel<<<ROWS, 256, 0, stream>>>(resid, gamma2, beta2, n2);

    if (single) {
        gemm_mt<1, 128, bf16><<<dim3(D_FF / 128, ROWS / 128), 256, 0, stream>>>(n2, fc1_b, hid, nullptr, nullptr, ROWS, D_FF, D_MODEL);
        gemm_mt<2, 64, float><<<dim3(D_MODEL / 64, ROWS / 128), 256, 0, stream>>>(hid, fc2_b, out, resid, nullptr, ROWS, D_MODEL, D_FF);
    } else {
        const int CHUNK = 4096;   // hid chunk = 32 MB in [24,56)
        for (int c = 0; c < ROWS / CHUNK; ++c) {
            const bf16*  n2c    = n2    + (size_t)c * CHUNK * D_MODEL;
            const float* residc = resid + (size_t)c * CHUNK * D_MODEL;
            float*       outc   = out   + (size_t)c * CHUNK * D_MODEL;
            gemm_mt<1, 128, bf16><<<dim3(D_FF / 128, CHUNK / 128), 256, 0, stream>>>(n2c, fc1_b, hid, nullptr, nullptr, CHUNK, D_FF, D_MODEL);
            gemm_mt<2, 64, float><<<dim3(D_MODEL / 64, CHUNK / 128), 256, 0, stream>>>(hid, fc2_b, outc, residc, nullptr, CHUNK, D_MODEL, D_FF);
        }
    }
}

// Round 9
// 608.286 us; speedup vs baseline: 18.0430x; 1.2052x over previous
//
#include <hip/hip_runtime.h>
#include <hip/hip_bf16.h>

#define D_MODEL 1024
#define N_HEADS 16
#define D_HEAD  64
#define D_FF    4096
#define BATCH   4
#define SEQ     2048
#define ROWS    (BATCH*SEQ)   // 8192
#define LN_EPS  1e-5f

typedef __bf16 bf16;
typedef __bf16 bf16x8 __attribute__((ext_vector_type(8)));
typedef float  f32x4  __attribute__((ext_vector_type(4)));

// ---- async global->LDS 16B copy: dst is WAVE-UNIFORM base, HW adds lane*16B ----
__device__ __forceinline__ void load16_lds(const bf16* g, bf16* l) {
#if defined(__has_builtin) && __has_builtin(__builtin_amdgcn_global_load_lds)
    __builtin_amdgcn_global_load_lds(
        (const __attribute__((address_space(1))) unsigned int*)g,
        (__attribute__((address_space(3))) unsigned int*)l,
        16, 0, 0);
#else
    const int lane = threadIdx.x & 63;
    ((bf16x8*)l)[lane] = *(const bf16x8*)g;
#endif
}

// ---------------- fp32 -> bf16 converts (batched) ----------------
__global__ __launch_bounds__(256) void f2b4_kernel(const float* a, const float* b,
                                                   const float* c, const float* d,
                                                   bf16* oa, bf16* ob, bf16* oc, bf16* od,
                                                   int n) {
    const float* srcs[4] = {a, b, c, d};
    bf16* dsts[4] = {oa, ob, oc, od};
    const float* s = srcs[blockIdx.y];
    bf16* dst = dsts[blockIdx.y];
    int i = blockIdx.x * 256 + threadIdx.x;
    int stride = gridDim.x * 256;
    for (; i < n; i += stride) dst[i] = (bf16)s[i];
}
__global__ __launch_bounds__(256) void f2b2_kernel(const float* a, const float* b,
                                                   bf16* oa, bf16* ob, int n) {
    const float* s = blockIdx.y ? b : a;
    bf16* dst = blockIdx.y ? ob : oa;
    int i = blockIdx.x * 256 + threadIdx.x;
    int stride = gridDim.x * 256;
    for (; i < n; i += stride) dst[i] = (bf16)s[i];
}

// ---------------- LayerNorm: fp32 in -> bf16 out, one block per row ----------------
__global__ __launch_bounds__(256) void ln_kernel(const float* __restrict__ x,
                                                 const float* __restrict__ gamma,
                                                 const float* __restrict__ beta,
                                                 bf16* __restrict__ out) {
    const int row = blockIdx.x;
    const int tid = threadIdx.x;
    const float* xr = x + (size_t)row * D_MODEL;

    float vals[4];
    float s = 0.f, ss = 0.f;
#pragma unroll
    for (int t = 0; t < 4; ++t) {
        float v = xr[tid + t * 256];
        vals[t] = v;
        s += v;
        ss += v * v;
    }
#pragma unroll
    for (int off = 32; off > 0; off >>= 1) {
        s  += __shfl_xor(s, off, 64);
        ss += __shfl_xor(ss, off, 64);
    }
    __shared__ float sbuf[4], ssbuf[4];
    const int wave = tid >> 6;
    if ((tid & 63) == 0) { sbuf[wave] = s; ssbuf[wave] = ss; }
    __syncthreads();
    s  = sbuf[0] + sbuf[1] + sbuf[2] + sbuf[3];
    ss = ssbuf[0] + ssbuf[1] + ssbuf[2] + ssbuf[3];

    const float mean = s * (1.f / D_MODEL);
    const float var  = ss * (1.f / D_MODEL) - mean * mean;
    const float inv  = rsqrtf(var + LN_EPS);

    bf16* orow = out + (size_t)row * D_MODEL;
#pragma unroll
    for (int t = 0; t < 4; ++t) {
        int c = tid + t * 256;
        orow[c] = (bf16)(gamma[c] * ((vals[t] - mean) * inv) + beta[c]);
    }
}

// ---------------- GELU (tanh approx, matches reference) ----------------
__device__ __forceinline__ float gelu_f(float x) {
    float c = x * x * x;
    return 0.5f * x * (1.f + tanhf(0.7978845608f * (x + 0.044715f * c)));
}

// ---------------- GEMM m97-style: C[M,N] = A[M,K] @ W[N,K]^T (+epilogue) ----------------
// EPI: 0 plain; 1 gelu; 2 v += ADD[idx] fp32 (C may alias ADD);
//      4 fused-QKV: cols [0,2048) -> C row stride 2048 (q pre-scaled 1/8 | k),
//        cols [2048,3072) -> VT transposed [B,H,dh,S] via per-wave LDS (TN=128 only).
template <int EPI, int TN, typename OutT>
__global__ __launch_bounds__(256) void gemm_mt(const bf16* __restrict__ A,
                                               const bf16* __restrict__ W,
                                               OutT* C,
                                               const float* ADD,
                                               bf16* VT,
                                               int M, int N, int K) {
    constexpr int WN = TN / 64;          // waves along N
    constexpr int WM = 4 / WN;           // waves along M
    constexpr int SM = (128 / WM) / 16;  // M-subtiles per wave

    __shared__ __align__(16) bf16 sA[128 * 32];
    __shared__ __align__(16) bf16 sB[TN * 32];
    __shared__ __align__(16) bf16 tbuf[EPI == 4 ? 4 * 64 * 72 : 4];

    const int wave = threadIdx.x >> 6;
    const int lane = threadIdx.x & 63;
    const int quad = lane >> 4;
    const int l16  = lane & 15;
    const int wm   = wave / WN;
    const int wn   = wave % WN;

    const int m0 = blockIdx.y * 128;
    const int n0 = blockIdx.x * TN;

    const int srow = lane >> 2;          // 0..15
    const int scol = (lane & 3) * 8;
    const bf16* gA0 = A + (size_t)(m0 + wave * 32 + srow) * K + scol;
    const bf16* gA1 = gA0 + (size_t)16 * K;
    bf16* lA0 = &sA[(wave * 32) * 32];
    bf16* lA1 = &sA[(wave * 32 + 16) * 32];
    const bf16* gB0 = W + (size_t)(n0 + wave * (TN / 4) + srow) * K + scol;
    const bf16* gB1 = gB0 + (size_t)16 * K;
    bf16* lB0 = &sB[(wave * (TN / 4)) * 32];
    bf16* lB1 = &sB[(wave * (TN / 4) + 16) * 32];

    f32x4 acc[SM][4] = {};

    for (int k0 = 0; k0 < K; k0 += 32) {
        load16_lds(gA0 + k0, lA0);
        load16_lds(gA1 + k0, lA1);
        load16_lds(gB0 + k0, lB0);
        if constexpr (TN == 128) load16_lds(gB1 + k0, lB1);
        __syncthreads();

        bf16x8 af[SM], bfr[4];
#pragma unroll
        for (int s = 0; s < SM; ++s)
            af[s] = *reinterpret_cast<const bf16x8*>(&sA[(wm * (128 / WM) + s * 16 + l16) * 32 + quad * 8]);
#pragma unroll
        for (int t = 0; t < 4; ++t)
            bfr[t] = *reinterpret_cast<const bf16x8*>(&sB[(wn * 64 + t * 16 + l16) * 32 + quad * 8]);
#pragma unroll
        for (int s = 0; s < SM; ++s)
#pragma unroll
            for (int t = 0; t < 4; ++t)
                acc[s][t] = __builtin_amdgcn_mfma_f32_16x16x32_bf16(af[s], bfr[t], acc[s][t], 0, 0, 0);
        __syncthreads();
    }

    if constexpr (EPI == 4) {
        if (n0 >= 2048) {
            // V columns: per-wave transpose through LDS (64x64, stride 72), store [B,H,dh,S]
            bf16* tw = &tbuf[wave * 64 * 72];
#pragma unroll
            for (int s = 0; s < SM; ++s)
#pragma unroll
                for (int t = 0; t < 4; ++t)
#pragma unroll
                    for (int r = 0; r < 4; ++r)
                        tw[(t * 16 + l16) * 72 + s * 16 + quad * 4 + r] = (bf16)acc[s][t][r];
#pragma unroll
            for (int i = 0; i < 8; ++i) {
                const int flat = i * 64 + lane;
                const int nl = flat >> 3;
                const int mc = flat & 7;
                bf16x8 v = *reinterpret_cast<const bf16x8*>(&tw[nl * 72 + mc * 8]);
                const int vcol = n0 - 2048 + wn * 64 + nl;
                const int m_glob = m0 + wm * 64 + mc * 8;
                const int bb = m_glob >> 11, sp = m_glob & (SEQ - 1);
                const int hh = vcol >> 6,  dh = vcol & 63;
                const size_t tidx = (((size_t)(bb * N_HEADS + hh) * D_HEAD + dh) << 11) + sp;
                *reinterpret_cast<bf16x8*>(&VT[tidx]) = v;
            }
        } else {
            // Q|K columns: row stride 2048; Q pre-scaled by 1/sqrt(dh)
            const float qscale = (n0 < 1024) ? 0.125f : 1.0f;
#pragma unroll
            for (int s = 0; s < SM; ++s) {
                const int mbase = m0 + wm * (128 / WM) + s * 16 + quad * 4;
#pragma unroll
                for (int t = 0; t < 4; ++t) {
                    const int n = n0 + wn * 64 + t * 16 + l16;
#pragma unroll
                    for (int r = 0; r < 4; ++r)
                        C[(size_t)(mbase + r) * 2048 + n] = (OutT)(acc[s][t][r] * qscale);
                }
            }
        }
    } else {
#pragma unroll
        for (int s = 0; s < SM; ++s) {
            const int mbase = m0 + wm * (128 / WM) + s * 16 + quad * 4;
#pragma unroll
            for (int t = 0; t < 4; ++t) {
                const int n = n0 + wn * 64 + t * 16 + l16;
#pragma unroll
                for (int r = 0; r < 4; ++r) {
                    float v = acc[s][t][r];
                    if (EPI == 1) v = gelu_f(v);
                    const size_t idx = (size_t)(mbase + r) * N + n;
                    if (EPI == 2) v += ADD[idx];
                    C[idx] = (OutT)v;
                }
            }
        }
    }
}

// ---------------- Flash attention: LDS-shared K/V, xor-swizzled, XCD-affine ----------------
// Grid 1024 x 256. id = bh%8 + 8*(pair + 16*(bh/8)): per-XCD head residency (R8-validated).
// Block handles q-tiles {pair, 31-pair} (uniform 33 K-tile iters). 4 waves x 16 q-rows,
// all sharing one 64-row q-tile; K/V tiles staged ONCE per block via global_load_lds
// (xor-swizzle on the global gather side -> conflict-optimal ds_read_b128).
__global__ __launch_bounds__(256) void flash_attn_kernel(const bf16* __restrict__ qk,
                                                         const bf16* __restrict__ vt,
                                                         bf16* __restrict__ o) {
    const int id   = blockIdx.x;
    const int bhl  = id & 7;
    const int rest = id >> 3;
    const int pair = rest & 15;
    const int bhh  = rest >> 4;
    const int bh   = bhh * 8 + bhl;
    const int b    = bh >> 4;
    const int h    = bh & 15;
    const int wave = threadIdx.x >> 6;
    const int lane = threadIdx.x & 63;
    const int quad = lane >> 4;
    const int l16  = lane & 15;

    __shared__ __align__(16) bf16 sK[64 * 64];   // [key][dh], chunks xor-swizzled
    __shared__ __align__(16) bf16 sV[64 * 64];   // [dh][key], chunks xor-swizzled
    __shared__ bf16 pbuf[4][16][68];

    const bf16* kbase = qk + (size_t)(b * SEQ) * 2048 + 1024 + h * D_HEAD;
    const bf16* vbase = vt + ((size_t)(bh * D_HEAD) << 11);   // [dh][S]

    const int lrow   = lane >> 3;              // 0..7 (row within 8-row staging group)
    const int lchunk = (lane & 7) ^ lrow;      // global chunk gathered into LDS slot lane&7
    const int xr     = l16 & 7;                // read-side xor (row & 7)

    bf16x8 ones;
#pragma unroll
    for (int i = 0; i < 8; ++i) ones[i] = (bf16)1.0f;

    for (int half = 0; half < 2; ++half) {
        const int qtile = half ? 31 - pair : pair;
        const int q0 = qtile * 64 + wave * 16;
        const size_t qrow = (size_t)(b * SEQ + q0 + l16) * 2048 + h * D_HEAD;
        bf16x8 qf0 = *reinterpret_cast<const bf16x8*>(qk + qrow + quad * 8);
        bf16x8 qf1 = *reinterpret_cast<const bf16x8*>(qk + qrow + 32 + quad * 8);

        f32x4 o_acc[4] = {(f32x4)(0.f), (f32x4)(0.f), (f32x4)(0.f), (f32x4)(0.f)};
        float m_q = -1e30f;
        float l_r[4] = {0.f, 0.f, 0.f, 0.f};

        for (int jt = 0; jt <= qtile; ++jt) {
            const int j0 = jt * 64;
            // ---- stage K,V tiles to LDS (each wave 16 rows of each; 2 instrs/tile) ----
            const bf16* gk = kbase + (size_t)(j0 + wave * 16 + lrow) * 2048 + lchunk * 8;
            const bf16* gv = vbase + (size_t)(wave * 16 + lrow) * 2048 + j0 + lchunk * 8;
            load16_lds(gk,            &sK[(wave * 16) * 64]);
            load16_lds(gk + 8 * 2048, &sK[(wave * 16 + 8) * 64]);
            load16_lds(gv,            &sV[(wave * 16) * 64]);
            load16_lds(gv + 8 * 2048, &sV[(wave * 16 + 8) * 64]);
            __syncthreads();

            // ---- QK^T (Q pre-scaled by 1/8 at projection) ----
            f32x4 s_acc[4] = {(f32x4)(0.f), (f32x4)(0.f), (f32x4)(0.f), (f32x4)(0.f)};
#pragma unroll
            for (int nb = 0; nb < 4; ++nb) {
                const int row = nb * 16 + l16;
                const int slot = quad ^ xr;
                bf16x8 kf0 = *reinterpret_cast<const bf16x8*>(&sK[row * 64 + slot * 8]);
                bf16x8 kf1 = *reinterpret_cast<const bf16x8*>(&sK[row * 64 + (slot ^ 4) * 8]);
                s_acc[nb] = __builtin_amdgcn_mfma_f32_16x16x32_bf16(qf0, kf0, s_acc[nb], 0, 0, 0);
                s_acc[nb] = __builtin_amdgcn_mfma_f32_16x16x32_bf16(qf1, kf1, s_acc[nb], 0, 0, 0);
            }
            // ---- causal mask (diag tile) + quad-local max (exact) ----
            const bool diag = (jt == qtile);
            float sv[4][4];
            float mx = -1e30f;
#pragma unroll
            for (int nb = 0; nb < 4; ++nb) {
                const int key = j0 + nb * 16 + l16;
#pragma unroll
                for (int r = 0; r < 4; ++r) {
                    float s = s_acc[nb][r];
                    if (diag && key > q0 + quad * 4 + r) s = -1e30f;
                    sv[nb][r] = s;
                    mx = fmaxf(mx, s);
                }
            }
#pragma unroll
            for (int off = 1; off < 16; off <<= 1) mx = fmaxf(mx, __shfl_xor(mx, off, 64));
            const float mn = fmaxf(m_q, mx);
            const float alpha = __expf(m_q - mn);
            m_q = mn;
            // ---- P = exp(S - m) -> LDS (C->A transform) ----
#pragma unroll
            for (int nb = 0; nb < 4; ++nb)
#pragma unroll
                for (int r = 0; r < 4; ++r)
                    pbuf[wave][quad * 4 + r][nb * 16 + l16] = (bf16)__expf(sv[nb][r] - mn);
#pragma unroll
            for (int r = 0; r < 4; ++r) l_r[r] *= alpha;
#pragma unroll
            for (int nb = 0; nb < 4; ++nb) o_acc[nb] *= alpha;
            bf16x8 pf0 = *reinterpret_cast<const bf16x8*>(&pbuf[wave][l16][quad * 8]);
            bf16x8 pf1 = *reinterpret_cast<const bf16x8*>(&pbuf[wave][l16][32 + quad * 8]);
            // ---- l += P @ ones ----
            f32x4 lt = (f32x4)(0.f);
            lt = __builtin_amdgcn_mfma_f32_16x16x32_bf16(pf0, ones, lt, 0, 0, 0);
            lt = __builtin_amdgcn_mfma_f32_16x16x32_bf16(pf1, ones, lt, 0, 0, 0);
#pragma unroll
            for (int r = 0; r < 4; ++r) l_r[r] += lt[r];
            // ---- O += P @ V ----
#pragma unroll
            for (int nb = 0; nb < 4; ++nb) {
                const int row = nb * 16 + l16;
                const int slot = quad ^ xr;
                bf16x8 vf0 = *reinterpret_cast<const bf16x8*>(&sV[row * 64 + slot * 8]);
                bf16x8 vf1 = *reinterpret_cast<const bf16x8*>(&sV[row * 64 + (slot ^ 4) * 8]);
                o_acc[nb] = __builtin_amdgcn_mfma_f32_16x16x32_bf16(pf0, vf0, o_acc[nb], 0, 0, 0);
                o_acc[nb] = __builtin_amdgcn_mfma_f32_16x16x32_bf16(pf1, vf1, o_acc[nb], 0, 0, 0);
            }
            __syncthreads();   // protect sK/sV until all waves done
        }
        // ---- epilogue: O /= l, store ----
#pragma unroll
        for (int nb = 0; nb < 4; ++nb) {
#pragma unroll
            for (int r = 0; r < 4; ++r) {
                const int qrow_g = q0 + quad * 4 + r;
                o[(size_t)(b * SEQ + qrow_g) * D_MODEL + h * D_HEAD + nb * 16 + l16] =
                    (bf16)(o_acc[nb][r] / l_r[r]);
            }
        }
    }
}

// ---------------- launch ----------------
// fp32 I/O. resid lives in d_out. Workspace (lifetime-aliased):
//   [0,24)   MB : bf16 weights wq|wk|wv (=wqkv) |wo|fc1|fc2
//   [24,40)  MB : n1 -> attn -> hid(start)
//   [40,72)  MB : qk [8192,2048] (dead after flash)
//   [72,88)  MB : vT (dead after flash)
//   MLP: if ws >= 104 MB: hid = [24,88), n2 = [88,104); else 2-chunk, n2 = [72,88).
extern "C" void kernel_launch(void* const* d_in, const int* in_sizes, int n_in,
                              void* d_out, int out_size, void* d_ws, size_t ws_size,
                              hipStream_t stream) {
    const float* x      = (const float*)d_in[0];
    const float* gamma1 = (const float*)d_in[1];
    const float* beta1  = (const float*)d_in[2];
    const float* wq     = (const float*)d_in[3];
    const float* wk     = (const float*)d_in[4];
    const float* wv     = (const float*)d_in[5];
    const float* wo     = (const float*)d_in[6];
    const float* gamma2 = (const float*)d_in[7];
    const float* beta2  = (const float*)d_in[8];
    const float* fc1    = (const float*)d_in[9];
    const float* fc2    = (const float*)d_in[10];
    float* out = (float*)d_out;

    const size_t WSMALL = (size_t)N_HEADS * D_HEAD * D_MODEL;  // 1,048,576
    const size_t WFF    = (size_t)D_FF * D_MODEL;              // 4,194,304
    const size_t RD     = (size_t)ROWS * D_MODEL;              // 8,388,608

    char* wsb = (char*)d_ws;
    bf16* wq_b  = (bf16*)(wsb);           // wq|wk|wv contiguous = wqkv [3072,1024]
    bf16* wk_b  = wq_b + WSMALL;
    bf16* wv_b  = wk_b + WSMALL;
    bf16* wo_b  = wv_b + WSMALL;
    bf16* fc1_b = wo_b + WSMALL;
    bf16* fc2_b = fc1_b + WFF;            // ends at 24 MB
    bf16* slotA = fc2_b + WFF;            // [24,40): n1 -> attn -> hid
    bf16* qkb   = slotA + RD;             // [40,72): q|k stride-2048
    bf16* vtb   = qkb + 2 * RD;           // [72,88)

    bf16* n1    = slotA;
    bf16* attnb = slotA;
    bf16* hid   = slotA;
    float* resid = out;

    const size_t need_single = (size_t)(24 + 64 + 16) * 1024 * 1024;
    const bool single = ws_size >= need_single;
    bf16* n2 = single ? (bf16*)(wsb + (size_t)88 * 1024 * 1024) : vtb;

    // weight conversion fp32 -> bf16
    f2b4_kernel<<<dim3(64, 4), 256, 0, stream>>>(wq, wk, wv, wo, wq_b, wk_b, wv_b, wo_b, (int)WSMALL);
    f2b2_kernel<<<dim3(256, 2), 256, 0, stream>>>(fc1, fc2, fc1_b, fc2_b, (int)WFF);

    // LN1
    ln_kernel<<<ROWS, 256, 0, stream>>>(x, gamma1, beta1, n1);
    // fused QKV: q (pre-scaled 1/8) | k -> qkb (stride 2048), v -> vtb (transposed)
    gemm_mt<4, 128, bf16><<<dim3(3072 / 128, ROWS / 128), 256, 0, stream>>>(n1, wq_b, qkb, nullptr, vtb, ROWS, 3072, D_MODEL);
    // flash attention (LDS-shared K/V, XCD-affine)
    flash_attn_kernel<<<1024, 256, 0, stream>>>(qkb, vtb, attnb);
    // resid(d_out) = x + attn @ wo^T
    gemm_mt<2, 64, float><<<dim3(D_MODEL / 64, ROWS / 128), 256, 0, stream>>>(attnb, wo_b, resid, x, nullptr, ROWS, D_MODEL, D_MODEL);
    // LN2
    ln_kernel<<<ROWS, 256, 0, stream>>>(resid, gamma2, beta2, n2);

    if (single) {
        gemm_mt<1, 128, bf16><<<dim3(D_FF / 128, ROWS / 128), 256, 0, stream>>>(n2, fc1_b, hid, nullptr, nullptr, ROWS, D_FF, D_MODEL);
        gemm_mt<2, 64, float><<<dim3(D_MODEL / 64, ROWS / 128), 256, 0, stream>>>(hid, fc2_b, out, resid, nullptr, ROWS, D_MODEL, D_FF);
    } else {
        const int CHUNK = 4096;   // hid chunk = 32 MB in [24,56)
        for (int c = 0; c < ROWS / CHUNK; ++c) {
            const bf16*  n2c    = n2    + (size_t)c * CHUNK * D_MODEL;
            const float* residc = resid + (size_t)c * CHUNK * D_MODEL;
            float*       outc   = out   + (size_t)c * CHUNK * D_MODEL;
            gemm_mt<1, 128, bf16><<<dim3(D_FF / 128, CHUNK / 128), 256, 0, stream>>>(n2c, fc1_b, hid, nullptr, nullptr, CHUNK, D_FF, D_MODEL);
            gemm_mt<2, 64, float><<<dim3(D_MODEL / 64, CHUNK / 128), 256, 0, stream>>>(hid, fc2_b, outc, residc, nullptr, CHUNK, D_MODEL, D_FF);
        }
    }
}

// Round 10
// 586.954 us; speedup vs baseline: 18.6987x; 1.0363x over previous
//
#include <hip/hip_runtime.h>
#include <hip/hip_bf16.h>

#define D_MODEL 1024
#define N_HEADS 16
#define D_HEAD  64
#define D_FF    4096
#define BATCH   4
#define SEQ     2048
#define ROWS    (BATCH*SEQ)   // 8192
#define LN_EPS  1e-5f

typedef __bf16 bf16;
typedef __bf16 bf16x8 __attribute__((ext_vector_type(8)));
typedef float  f32x4  __attribute__((ext_vector_type(4)));

// ---- async global->LDS 16B copy: dst is WAVE-UNIFORM base, HW adds lane*16B ----
__device__ __forceinline__ void load16_lds(const bf16* g, bf16* l) {
#if defined(__has_builtin) && __has_builtin(__builtin_amdgcn_global_load_lds)
    __builtin_amdgcn_global_load_lds(
        (const __attribute__((address_space(1))) unsigned int*)g,
        (__attribute__((address_space(3))) unsigned int*)l,
        16, 0, 0);
#else
    const int lane = threadIdx.x & 63;
    ((bf16x8*)l)[lane] = *(const bf16x8*)g;
#endif
}

// ---------------- fp32 -> bf16 converts (batched) ----------------
__global__ __launch_bounds__(256) void f2b4_kernel(const float* a, const float* b,
                                                   const float* c, const float* d,
                                                   bf16* oa, bf16* ob, bf16* oc, bf16* od,
                                                   int n) {
    const float* srcs[4] = {a, b, c, d};
    bf16* dsts[4] = {oa, ob, oc, od};
    const float* s = srcs[blockIdx.y];
    bf16* dst = dsts[blockIdx.y];
    int i = blockIdx.x * 256 + threadIdx.x;
    int stride = gridDim.x * 256;
    for (; i < n; i += stride) dst[i] = (bf16)s[i];
}
__global__ __launch_bounds__(256) void f2b2_kernel(const float* a, const float* b,
                                                   bf16* oa, bf16* ob, int n) {
    const float* s = blockIdx.y ? b : a;
    bf16* dst = blockIdx.y ? ob : oa;
    int i = blockIdx.x * 256 + threadIdx.x;
    int stride = gridDim.x * 256;
    for (; i < n; i += stride) dst[i] = (bf16)s[i];
}

// ---------------- LayerNorm: fp32 in -> bf16 out, one block per row ----------------
__global__ __launch_bounds__(256) void ln_kernel(const float* __restrict__ x,
                                                 const float* __restrict__ gamma,
                                                 const float* __restrict__ beta,
                                                 bf16* __restrict__ out) {
    const int row = blockIdx.x;
    const int tid = threadIdx.x;
    const float* xr = x + (size_t)row * D_MODEL;

    float vals[4];
    float s = 0.f, ss = 0.f;
#pragma unroll
    for (int t = 0; t < 4; ++t) {
        float v = xr[tid + t * 256];
        vals[t] = v;
        s += v;
        ss += v * v;
    }
#pragma unroll
    for (int off = 32; off > 0; off >>= 1) {
        s  += __shfl_xor(s, off, 64);
        ss += __shfl_xor(ss, off, 64);
    }
    __shared__ float sbuf[4], ssbuf[4];
    const int wave = tid >> 6;
    if ((tid & 63) == 0) { sbuf[wave] = s; ssbuf[wave] = ss; }
    __syncthreads();
    s  = sbuf[0] + sbuf[1] + sbuf[2] + sbuf[3];
    ss = ssbuf[0] + ssbuf[1] + ssbuf[2] + ssbuf[3];

    const float mean = s * (1.f / D_MODEL);
    const float var  = ss * (1.f / D_MODEL) - mean * mean;
    const float inv  = rsqrtf(var + LN_EPS);

    bf16* orow = out + (size_t)row * D_MODEL;
#pragma unroll
    for (int t = 0; t < 4; ++t) {
        int c = tid + t * 256;
        orow[c] = (bf16)(gamma[c] * ((vals[t] - mean) * inv) + beta[c]);
    }
}

// ---------------- GELU (tanh approx, matches reference) ----------------
__device__ __forceinline__ float gelu_f(float x) {
    float c = x * x * x;
    return 0.5f * x * (1.f + tanhf(0.7978845608f * (x + 0.044715f * c)));
}

// ---------------- GEMM m97-style, XCD-affine swizzle ----------------
// 1D grid of (N/TN)*(M/128) blocks. Block id b: xcd = b&7 (HW round-robin), j = b>>3;
// bx = j % nN, band = (j/nN)*8 + xcd  -> each XCD runs all N-blocks of one M-band
// consecutively, so the A-band (1 MB) lives in that XCD's L2 (R8-validated trick).
// Requires (M/128) % 8 == 0.
// EPI: 0 plain; 1 gelu; 2 v += ADD[idx] fp32 (C may alias ADD);
//      4 fused-QKV: cols [0,2048) -> C row stride 2048 (q pre-scaled 1/8 | k),
//        cols [2048,3072) -> VT transposed [B,H,dh,S] via per-wave LDS (TN=128 only).
template <int EPI, int TN, typename OutT>
__global__ __launch_bounds__(256) void gemm_mt(const bf16* __restrict__ A,
                                               const bf16* __restrict__ W,
                                               OutT* C,
                                               const float* ADD,
                                               bf16* VT,
                                               int M, int N, int K) {
    constexpr int WN = TN / 64;          // waves along N
    constexpr int WM = 4 / WN;           // waves along M
    constexpr int SM = (128 / WM) / 16;  // M-subtiles per wave

    __shared__ __align__(16) bf16 sA[128 * 32];
    __shared__ __align__(16) bf16 sB[TN * 32];
    __shared__ __align__(16) bf16 tbuf[EPI == 4 ? 4 * 64 * 72 : 4];

    const int wave = threadIdx.x >> 6;
    const int lane = threadIdx.x & 63;
    const int quad = lane >> 4;
    const int l16  = lane & 15;
    const int wm   = wave / WN;
    const int wn   = wave % WN;

    // XCD-affine decode
    const int nN  = N / TN;
    const int b   = blockIdx.x;
    const int xcd = b & 7;
    const int j   = b >> 3;
    const int bx  = j % nN;
    const int band = (j / nN) * 8 + xcd;

    const int m0 = band * 128;
    const int n0 = bx * TN;

    const int srow = lane >> 2;          // 0..15
    const int scol = (lane & 3) * 8;
    const bf16* gA0 = A + (size_t)(m0 + wave * 32 + srow) * K + scol;
    const bf16* gA1 = gA0 + (size_t)16 * K;
    bf16* lA0 = &sA[(wave * 32) * 32];
    bf16* lA1 = &sA[(wave * 32 + 16) * 32];
    const bf16* gB0 = W + (size_t)(n0 + wave * (TN / 4) + srow) * K + scol;
    const bf16* gB1 = gB0 + (size_t)16 * K;
    bf16* lB0 = &sB[(wave * (TN / 4)) * 32];
    bf16* lB1 = &sB[(wave * (TN / 4) + 16) * 32];

    f32x4 acc[SM][4] = {};

    for (int k0 = 0; k0 < K; k0 += 32) {
        load16_lds(gA0 + k0, lA0);
        load16_lds(gA1 + k0, lA1);
        load16_lds(gB0 + k0, lB0);
        if constexpr (TN == 128) load16_lds(gB1 + k0, lB1);
        __syncthreads();

        bf16x8 af[SM], bfr[4];
#pragma unroll
        for (int s = 0; s < SM; ++s)
            af[s] = *reinterpret_cast<const bf16x8*>(&sA[(wm * (128 / WM) + s * 16 + l16) * 32 + quad * 8]);
#pragma unroll
        for (int t = 0; t < 4; ++t)
            bfr[t] = *reinterpret_cast<const bf16x8*>(&sB[(wn * 64 + t * 16 + l16) * 32 + quad * 8]);
#pragma unroll
        for (int s = 0; s < SM; ++s)
#pragma unroll
            for (int t = 0; t < 4; ++t)
                acc[s][t] = __builtin_amdgcn_mfma_f32_16x16x32_bf16(af[s], bfr[t], acc[s][t], 0, 0, 0);
        __syncthreads();
    }

    if constexpr (EPI == 4) {
        if (n0 >= 2048) {
            // V columns: per-wave transpose through LDS (64x64, stride 72), store [B,H,dh,S]
            bf16* tw = &tbuf[wave * 64 * 72];
#pragma unroll
            for (int s = 0; s < SM; ++s)
#pragma unroll
                for (int t = 0; t < 4; ++t)
#pragma unroll
                    for (int r = 0; r < 4; ++r)
                        tw[(t * 16 + l16) * 72 + s * 16 + quad * 4 + r] = (bf16)acc[s][t][r];
#pragma unroll
            for (int i = 0; i < 8; ++i) {
                const int flat = i * 64 + lane;
                const int nl = flat >> 3;
                const int mc = flat & 7;
                bf16x8 v = *reinterpret_cast<const bf16x8*>(&tw[nl * 72 + mc * 8]);
                const int vcol = n0 - 2048 + wn * 64 + nl;
                const int m_glob = m0 + wm * 64 + mc * 8;
                const int bb = m_glob >> 11, sp = m_glob & (SEQ - 1);
                const int hh = vcol >> 6,  dh = vcol & 63;
                const size_t tidx = (((size_t)(bb * N_HEADS + hh) * D_HEAD + dh) << 11) + sp;
                *reinterpret_cast<bf16x8*>(&VT[tidx]) = v;
            }
        } else {
            // Q|K columns: row stride 2048; Q pre-scaled by 1/sqrt(dh)
            const float qscale = (n0 < 1024) ? 0.125f : 1.0f;
#pragma unroll
            for (int s = 0; s < SM; ++s) {
                const int mbase = m0 + wm * (128 / WM) + s * 16 + quad * 4;
#pragma unroll
                for (int t = 0; t < 4; ++t) {
                    const int n = n0 + wn * 64 + t * 16 + l16;
#pragma unroll
                    for (int r = 0; r < 4; ++r)
                        C[(size_t)(mbase + r) * 2048 + n] = (OutT)(acc[s][t][r] * qscale);
                }
            }
        }
    } else {
#pragma unroll
        for (int s = 0; s < SM; ++s) {
            const int mbase = m0 + wm * (128 / WM) + s * 16 + quad * 4;
#pragma unroll
            for (int t = 0; t < 4; ++t) {
                const int n = n0 + wn * 64 + t * 16 + l16;
#pragma unroll
                for (int r = 0; r < 4; ++r) {
                    float v = acc[s][t][r];
                    if (EPI == 1) v = gelu_f(v);
                    const size_t idx = (size_t)(mbase + r) * N + n;
                    if (EPI == 2) v += ADD[idx];
                    C[idx] = (OutT)v;
                }
            }
        }
    }
}

// ---------------- Flash attention: LDS-shared K/V, xor-swizzled, XCD-affine ----------------
__global__ __launch_bounds__(256) void flash_attn_kernel(const bf16* __restrict__ qk,
                                                         const bf16* __restrict__ vt,
                                                         bf16* __restrict__ o) {
    const int id   = blockIdx.x;
    const int bhl  = id & 7;
    const int rest = id >> 3;
    const int pair = rest & 15;
    const int bhh  = rest >> 4;
    const int bh   = bhh * 8 + bhl;
    const int b    = bh >> 4;
    const int h    = bh & 15;
    const int wave = threadIdx.x >> 6;
    const int lane = threadIdx.x & 63;
    const int quad = lane >> 4;
    const int l16  = lane & 15;

    __shared__ __align__(16) bf16 sK[64 * 64];   // [key][dh], chunks xor-swizzled
    __shared__ __align__(16) bf16 sV[64 * 64];   // [dh][key], chunks xor-swizzled
    __shared__ bf16 pbuf[4][16][68];

    const bf16* kbase = qk + (size_t)(b * SEQ) * 2048 + 1024 + h * D_HEAD;
    const bf16* vbase = vt + ((size_t)(bh * D_HEAD) << 11);   // [dh][S]

    const int lrow   = lane >> 3;              // 0..7
    const int lchunk = (lane & 7) ^ lrow;      // gather-side xor swizzle
    const int xr     = l16 & 7;                // read-side xor

    bf16x8 ones;
#pragma unroll
    for (int i = 0; i < 8; ++i) ones[i] = (bf16)1.0f;

    for (int half = 0; half < 2; ++half) {
        const int qtile = half ? 31 - pair : pair;
        const int q0 = qtile * 64 + wave * 16;
        const size_t qrow = (size_t)(b * SEQ + q0 + l16) * 2048 + h * D_HEAD;
        bf16x8 qf0 = *reinterpret_cast<const bf16x8*>(qk + qrow + quad * 8);
        bf16x8 qf1 = *reinterpret_cast<const bf16x8*>(qk + qrow + 32 + quad * 8);

        f32x4 o_acc[4] = {(f32x4)(0.f), (f32x4)(0.f), (f32x4)(0.f), (f32x4)(0.f)};
        float m_q = -1e30f;
        float l_r[4] = {0.f, 0.f, 0.f, 0.f};

        for (int jt = 0; jt <= qtile; ++jt) {
            const int j0 = jt * 64;
            const bf16* gk = kbase + (size_t)(j0 + wave * 16 + lrow) * 2048 + lchunk * 8;
            const bf16* gv = vbase + (size_t)(wave * 16 + lrow) * 2048 + j0 + lchunk * 8;
            load16_lds(gk,            &sK[(wave * 16) * 64]);
            load16_lds(gk + 8 * 2048, &sK[(wave * 16 + 8) * 64]);
            load16_lds(gv,            &sV[(wave * 16) * 64]);
            load16_lds(gv + 8 * 2048, &sV[(wave * 16 + 8) * 64]);
            __syncthreads();

            f32x4 s_acc[4] = {(f32x4)(0.f), (f32x4)(0.f), (f32x4)(0.f), (f32x4)(0.f)};
#pragma unroll
            for (int nb = 0; nb < 4; ++nb) {
                const int row = nb * 16 + l16;
                const int slot = quad ^ xr;
                bf16x8 kf0 = *reinterpret_cast<const bf16x8*>(&sK[row * 64 + slot * 8]);
                bf16x8 kf1 = *reinterpret_cast<const bf16x8*>(&sK[row * 64 + (slot ^ 4) * 8]);
                s_acc[nb] = __builtin_amdgcn_mfma_f32_16x16x32_bf16(qf0, kf0, s_acc[nb], 0, 0, 0);
                s_acc[nb] = __builtin_amdgcn_mfma_f32_16x16x32_bf16(qf1, kf1, s_acc[nb], 0, 0, 0);
            }
            const bool diag = (jt == qtile);
            float sv[4][4];
            float mx = -1e30f;
#pragma unroll
            for (int nb = 0; nb < 4; ++nb) {
                const int key = j0 + nb * 16 + l16;
#pragma unroll
                for (int r = 0; r < 4; ++r) {
                    float s = s_acc[nb][r];
                    if (diag && key > q0 + quad * 4 + r) s = -1e30f;
                    sv[nb][r] = s;
                    mx = fmaxf(mx, s);
                }
            }
#pragma unroll
            for (int off = 1; off < 16; off <<= 1) mx = fmaxf(mx, __shfl_xor(mx, off, 64));
            const float mn = fmaxf(m_q, mx);
            const float alpha = __expf(m_q - mn);
            m_q = mn;
#pragma unroll
            for (int nb = 0; nb < 4; ++nb)
#pragma unroll
                for (int r = 0; r < 4; ++r)
                    pbuf[wave][quad * 4 + r][nb * 16 + l16] = (bf16)__expf(sv[nb][r] - mn);
#pragma unroll
            for (int r = 0; r < 4; ++r) l_r[r] *= alpha;
#pragma unroll
            for (int nb = 0; nb < 4; ++nb) o_acc[nb] *= alpha;
            bf16x8 pf0 = *reinterpret_cast<const bf16x8*>(&pbuf[wave][l16][quad * 8]);
            bf16x8 pf1 = *reinterpret_cast<const bf16x8*>(&pbuf[wave][l16][32 + quad * 8]);
            f32x4 lt = (f32x4)(0.f);
            lt = __builtin_amdgcn_mfma_f32_16x16x32_bf16(pf0, ones, lt, 0, 0, 0);
            lt = __builtin_amdgcn_mfma_f32_16x16x32_bf16(pf1, ones, lt, 0, 0, 0);
#pragma unroll
            for (int r = 0; r < 4; ++r) l_r[r] += lt[r];
#pragma unroll
            for (int nb = 0; nb < 4; ++nb) {
                const int row = nb * 16 + l16;
                const int slot = quad ^ xr;
                bf16x8 vf0 = *reinterpret_cast<const bf16x8*>(&sV[row * 64 + slot * 8]);
                bf16x8 vf1 = *reinterpret_cast<const bf16x8*>(&sV[row * 64 + (slot ^ 4) * 8]);
                o_acc[nb] = __builtin_amdgcn_mfma_f32_16x16x32_bf16(pf0, vf0, o_acc[nb], 0, 0, 0);
                o_acc[nb] = __builtin_amdgcn_mfma_f32_16x16x32_bf16(pf1, vf1, o_acc[nb], 0, 0, 0);
            }
            __syncthreads();
        }
#pragma unroll
        for (int nb = 0; nb < 4; ++nb) {
#pragma unroll
            for (int r = 0; r < 4; ++r) {
                const int qrow_g = q0 + quad * 4 + r;
                o[(size_t)(b * SEQ + qrow_g) * D_MODEL + h * D_HEAD + nb * 16 + l16] =
                    (bf16)(o_acc[nb][r] / l_r[r]);
            }
        }
    }
}

// ---------------- launch ----------------
// fp32 I/O. resid lives in d_out. Workspace (lifetime-aliased):
//   [0,24)   MB : bf16 weights wq|wk|wv (=wqkv) |wo|fc1|fc2
//   [24,40)  MB : n1 -> attn -> hid(start)
//   [40,72)  MB : qk [8192,2048] (dead after flash)
//   [72,88)  MB : vT (dead after flash)
//   MLP: if ws >= 104 MB: hid = [24,88), n2 = [88,104); else 2-chunk, n2 = [72,88).
extern "C" void kernel_launch(void* const* d_in, const int* in_sizes, int n_in,
                              void* d_out, int out_size, void* d_ws, size_t ws_size,
                              hipStream_t stream) {
    const float* x      = (const float*)d_in[0];
    const float* gamma1 = (const float*)d_in[1];
    const float* beta1  = (const float*)d_in[2];
    const float* wq     = (const float*)d_in[3];
    const float* wk     = (const float*)d_in[4];
    const float* wv     = (const float*)d_in[5];
    const float* wo     = (const float*)d_in[6];
    const float* gamma2 = (const float*)d_in[7];
    const float* beta2  = (const float*)d_in[8];
    const float* fc1    = (const float*)d_in[9];
    const float* fc2    = (const float*)d_in[10];
    float* out = (float*)d_out;

    const size_t WSMALL = (size_t)N_HEADS * D_HEAD * D_MODEL;  // 1,048,576
    const size_t WFF    = (size_t)D_FF * D_MODEL;              // 4,194,304
    const size_t RD     = (size_t)ROWS * D_MODEL;              // 8,388,608

    char* wsb = (char*)d_ws;
    bf16* wq_b  = (bf16*)(wsb);           // wq|wk|wv contiguous = wqkv [3072,1024]
    bf16* wk_b  = wq_b + WSMALL;
    bf16* wv_b  = wk_b + WSMALL;
    bf16* wo_b  = wv_b + WSMALL;
    bf16* fc1_b = wo_b + WSMALL;
    bf16* fc2_b = fc1_b + WFF;            // ends at 24 MB
    bf16* slotA = fc2_b + WFF;            // [24,40): n1 -> attn -> hid
    bf16* qkb   = slotA + RD;             // [40,72): q|k stride-2048
    bf16* vtb   = qkb + 2 * RD;           // [72,88)

    bf16* n1    = slotA;
    bf16* attnb = slotA;
    bf16* hid   = slotA;
    float* resid = out;

    const size_t need_single = (size_t)(24 + 64 + 16) * 1024 * 1024;
    const bool single = ws_size >= need_single;
    bf16* n2 = single ? (bf16*)(wsb + (size_t)88 * 1024 * 1024) : vtb;

    // weight conversion fp32 -> bf16
    f2b4_kernel<<<dim3(64, 4), 256, 0, stream>>>(wq, wk, wv, wo, wq_b, wk_b, wv_b, wo_b, (int)WSMALL);
    f2b2_kernel<<<dim3(256, 2), 256, 0, stream>>>(fc1, fc2, fc1_b, fc2_b, (int)WFF);

    // LN1
    ln_kernel<<<ROWS, 256, 0, stream>>>(x, gamma1, beta1, n1);
    // fused QKV (1D XCD-affine grid): q (pre-scaled 1/8)|k -> qkb, v -> vtb transposed
    gemm_mt<4, 128, bf16><<<(3072 / 128) * (ROWS / 128), 256, 0, stream>>>(n1, wq_b, qkb, nullptr, vtb, ROWS, 3072, D_MODEL);
    // flash attention (LDS-shared K/V, XCD-affine)
    flash_attn_kernel<<<1024, 256, 0, stream>>>(qkb, vtb, attnb);
    // resid(d_out) = x + attn @ wo^T
    gemm_mt<2, 64, float><<<(D_MODEL / 64) * (ROWS / 128), 256, 0, stream>>>(attnb, wo_b, resid, x, nullptr, ROWS, D_MODEL, D_MODEL);
    // LN2
    ln_kernel<<<ROWS, 256, 0, stream>>>(resid, gamma2, beta2, n2);

    if (single) {
        gemm_mt<1, 128, bf16><<<(D_FF / 128) * (ROWS / 128), 256, 0, stream>>>(n2, fc1_b, hid, nullptr, nullptr, ROWS, D_FF, D_MODEL);
        gemm_mt<2, 64, float><<<(D_MODEL / 64) * (ROWS / 128), 256, 0, stream>>>(hid, fc2_b, out, resid, nullptr, ROWS, D_MODEL, D_FF);
    } else {
        const int CHUNK = 4096;   // hid chunk = 32 MB in [24,56); CHUNK/128 = 32 (div by 8 ok)
        for (int c = 0; c < ROWS / CHUNK; ++c) {
            const bf16*  n2c    = n2    + (size_t)c * CHUNK * D_MODEL;
            const float* residc = resid + (size_t)c * CHUNK * D_MODEL;
            float*       outc   = out   + (size_t)c * CHUNK * D_MODEL;
            gemm_mt<1, 128, bf16><<<(D_FF / 128) * (CHUNK / 128), 256, 0, stream>>>(n2c, fc1_b, hid, nullptr, nullptr, CHUNK, D_FF, D_MODEL);
            gemm_mt<2, 64, float><<<(D_MODEL / 64) * (CHUNK / 128), 256, 0, stream>>>(hid, fc2_b, outc, residc, nullptr, CHUNK, D_MODEL, D_FF);
        }
    }
}

// Round 11
// 586.469 us; speedup vs baseline: 18.7142x; 1.0008x over previous
//
#include <hip/hip_runtime.h>
#include <hip/hip_bf16.h>

#define D_MODEL 1024
#define N_HEADS 16
#define D_HEAD  64
#define D_FF    4096
#define BATCH   4
#define SEQ     2048
#define ROWS    (BATCH*SEQ)   // 8192
#define LN_EPS  1e-5f

typedef __bf16 bf16;
typedef __bf16 bf16x8 __attribute__((ext_vector_type(8)));
typedef float  f32x4  __attribute__((ext_vector_type(4)));

// ---- async global->LDS 16B copy: dst is WAVE-UNIFORM base, HW adds lane*16B ----
__device__ __forceinline__ void load16_lds(const bf16* g, bf16* l) {
#if defined(__has_builtin) && __has_builtin(__builtin_amdgcn_global_load_lds)
    __builtin_amdgcn_global_load_lds(
        (const __attribute__((address_space(1))) unsigned int*)g,
        (__attribute__((address_space(3))) unsigned int*)l,
        16, 0, 0);
#else
    const int lane = threadIdx.x & 63;
    ((bf16x8*)l)[lane] = *(const bf16x8*)g;
#endif
}

// ---------------- fp32 -> bf16 converts (batched) ----------------
__global__ __launch_bounds__(256) void f2b4_kernel(const float* a, const float* b,
                                                   const float* c, const float* d,
                                                   bf16* oa, bf16* ob, bf16* oc, bf16* od,
                                                   int n) {
    const float* srcs[4] = {a, b, c, d};
    bf16* dsts[4] = {oa, ob, oc, od};
    const float* s = srcs[blockIdx.y];
    bf16* dst = dsts[blockIdx.y];
    int i = blockIdx.x * 256 + threadIdx.x;
    int stride = gridDim.x * 256;
    for (; i < n; i += stride) dst[i] = (bf16)s[i];
}
__global__ __launch_bounds__(256) void f2b2_kernel(const float* a, const float* b,
                                                   bf16* oa, bf16* ob, int n) {
    const float* s = blockIdx.y ? b : a;
    bf16* dst = blockIdx.y ? ob : oa;
    int i = blockIdx.x * 256 + threadIdx.x;
    int stride = gridDim.x * 256;
    for (; i < n; i += stride) dst[i] = (bf16)s[i];
}

// ---------------- LayerNorm: fp32 in -> bf16 out, one block per row ----------------
__global__ __launch_bounds__(256) void ln_kernel(const float* __restrict__ x,
                                                 const float* __restrict__ gamma,
                                                 const float* __restrict__ beta,
                                                 bf16* __restrict__ out) {
    const int row = blockIdx.x;
    const int tid = threadIdx.x;
    const float* xr = x + (size_t)row * D_MODEL;

    float vals[4];
    float s = 0.f, ss = 0.f;
#pragma unroll
    for (int t = 0; t < 4; ++t) {
        float v = xr[tid + t * 256];
        vals[t] = v;
        s += v;
        ss += v * v;
    }
#pragma unroll
    for (int off = 32; off > 0; off >>= 1) {
        s  += __shfl_xor(s, off, 64);
        ss += __shfl_xor(ss, off, 64);
    }
    __shared__ float sbuf[4], ssbuf[4];
    const int wave = tid >> 6;
    if ((tid & 63) == 0) { sbuf[wave] = s; ssbuf[wave] = ss; }
    __syncthreads();
    s  = sbuf[0] + sbuf[1] + sbuf[2] + sbuf[3];
    ss = ssbuf[0] + ssbuf[1] + ssbuf[2] + ssbuf[3];

    const float mean = s * (1.f / D_MODEL);
    const float var  = ss * (1.f / D_MODEL) - mean * mean;
    const float inv  = rsqrtf(var + LN_EPS);

    bf16* orow = out + (size_t)row * D_MODEL;
#pragma unroll
    for (int t = 0; t < 4; ++t) {
        int c = tid + t * 256;
        orow[c] = (bf16)(gamma[c] * ((vals[t] - mean) * inv) + beta[c]);
    }
}

// ---------------- GELU: 0.5x(1+tanh(y)) == x/(1+exp(-2y)), hardware v_exp_f32 ----------------
// Exact identity with the reference's tanh formulation; ~8 VALU ops vs ~40 for tanhf.
__device__ __forceinline__ float gelu_f(float x) {
    const float y = x * (0.7978845608f + 0.0356774081f * x * x);  // 0.7978845608*(x+0.044715x^3)
    return x / (1.f + __expf(-2.f * y));
}

// ---------------- GEMM m97-style, XCD-affine swizzle ----------------
// 1D grid of (N/TN)*(M/128) blocks. Block id b: xcd = b&7 (HW round-robin), j = b>>3;
// bx = j % nN, band = (j/nN)*8 + xcd  -> each XCD runs all N-blocks of one M-band
// consecutively, so the A-band (1 MB) lives in that XCD's L2 (R8/R10-validated).
// Requires (M/128) % 8 == 0.
// EPI: 0 plain; 1 gelu; 2 v += ADD[idx] fp32 (C may alias ADD);
//      4 fused-QKV: cols [0,2048) -> C row stride 2048 (q pre-scaled 1/8 | k),
//        cols [2048,3072) -> VT transposed [B,H,dh,S] via per-wave LDS (TN=128 only).
template <int EPI, int TN, typename OutT>
__global__ __launch_bounds__(256) void gemm_mt(const bf16* __restrict__ A,
                                               const bf16* __restrict__ W,
                                               OutT* C,
                                               const float* ADD,
                                               bf16* VT,
                                               int M, int N, int K) {
    constexpr int WN = TN / 64;          // waves along N
    constexpr int WM = 4 / WN;           // waves along M
    constexpr int SM = (128 / WM) / 16;  // M-subtiles per wave

    __shared__ __align__(16) bf16 sA[128 * 32];
    __shared__ __align__(16) bf16 sB[TN * 32];
    __shared__ __align__(16) bf16 tbuf[EPI == 4 ? 4 * 64 * 72 : 4];

    const int wave = threadIdx.x >> 6;
    const int lane = threadIdx.x & 63;
    const int quad = lane >> 4;
    const int l16  = lane & 15;
    const int wm   = wave / WN;
    const int wn   = wave % WN;

    // XCD-affine decode
    const int nN  = N / TN;
    const int b   = blockIdx.x;
    const int xcd = b & 7;
    const int j   = b >> 3;
    const int bx  = j % nN;
    const int band = (j / nN) * 8 + xcd;

    const int m0 = band * 128;
    const int n0 = bx * TN;

    const int srow = lane >> 2;          // 0..15
    const int scol = (lane & 3) * 8;
    const bf16* gA0 = A + (size_t)(m0 + wave * 32 + srow) * K + scol;
    const bf16* gA1 = gA0 + (size_t)16 * K;
    bf16* lA0 = &sA[(wave * 32) * 32];
    bf16* lA1 = &sA[(wave * 32 + 16) * 32];
    const bf16* gB0 = W + (size_t)(n0 + wave * (TN / 4) + srow) * K + scol;
    const bf16* gB1 = gB0 + (size_t)16 * K;
    bf16* lB0 = &sB[(wave * (TN / 4)) * 32];
    bf16* lB1 = &sB[(wave * (TN / 4) + 16) * 32];

    f32x4 acc[SM][4] = {};

    for (int k0 = 0; k0 < K; k0 += 32) {
        load16_lds(gA0 + k0, lA0);
        load16_lds(gA1 + k0, lA1);
        load16_lds(gB0 + k0, lB0);
        if constexpr (TN == 128) load16_lds(gB1 + k0, lB1);
        __syncthreads();

        bf16x8 af[SM], bfr[4];
#pragma unroll
        for (int s = 0; s < SM; ++s)
            af[s] = *reinterpret_cast<const bf16x8*>(&sA[(wm * (128 / WM) + s * 16 + l16) * 32 + quad * 8]);
#pragma unroll
        for (int t = 0; t < 4; ++t)
            bfr[t] = *reinterpret_cast<const bf16x8*>(&sB[(wn * 64 + t * 16 + l16) * 32 + quad * 8]);
#pragma unroll
        for (int s = 0; s < SM; ++s)
#pragma unroll
            for (int t = 0; t < 4; ++t)
                acc[s][t] = __builtin_amdgcn_mfma_f32_16x16x32_bf16(af[s], bfr[t], acc[s][t], 0, 0, 0);
        __syncthreads();
    }

    if constexpr (EPI == 4) {
        if (n0 >= 2048) {
            // V columns: per-wave transpose through LDS (64x64, stride 72), store [B,H,dh,S]
            bf16* tw = &tbuf[wave * 64 * 72];
#pragma unroll
            for (int s = 0; s < SM; ++s)
#pragma unroll
                for (int t = 0; t < 4; ++t)
#pragma unroll
                    for (int r = 0; r < 4; ++r)
                        tw[(t * 16 + l16) * 72 + s * 16 + quad * 4 + r] = (bf16)acc[s][t][r];
#pragma unroll
            for (int i = 0; i < 8; ++i) {
                const int flat = i * 64 + lane;
                const int nl = flat >> 3;
                const int mc = flat & 7;
                bf16x8 v = *reinterpret_cast<const bf16x8*>(&tw[nl * 72 + mc * 8]);
                const int vcol = n0 - 2048 + wn * 64 + nl;
                const int m_glob = m0 + wm * 64 + mc * 8;
                const int bb = m_glob >> 11, sp = m_glob & (SEQ - 1);
                const int hh = vcol >> 6,  dh = vcol & 63;
                const size_t tidx = (((size_t)(bb * N_HEADS + hh) * D_HEAD + dh) << 11) + sp;
                *reinterpret_cast<bf16x8*>(&VT[tidx]) = v;
            }
        } else {
            // Q|K columns: row stride 2048; Q pre-scaled by 1/sqrt(dh)
            const float qscale = (n0 < 1024) ? 0.125f : 1.0f;
#pragma unroll
            for (int s = 0; s < SM; ++s) {
                const int mbase = m0 + wm * (128 / WM) + s * 16 + quad * 4;
#pragma unroll
                for (int t = 0; t < 4; ++t) {
                    const int n = n0 + wn * 64 + t * 16 + l16;
#pragma unroll
                    for (int r = 0; r < 4; ++r)
                        C[(size_t)(mbase + r) * 2048 + n] = (OutT)(acc[s][t][r] * qscale);
                }
            }
        }
    } else {
#pragma unroll
        for (int s = 0; s < SM; ++s) {
            const int mbase = m0 + wm * (128 / WM) + s * 16 + quad * 4;
#pragma unroll
            for (int t = 0; t < 4; ++t) {
                const int n = n0 + wn * 64 + t * 16 + l16;
#pragma unroll
                for (int r = 0; r < 4; ++r) {
                    float v = acc[s][t][r];
                    if (EPI == 1) v = gelu_f(v);
                    const size_t idx = (size_t)(mbase + r) * N + n;
                    if (EPI == 2) v += ADD[idx];
                    C[idx] = (OutT)v;
                }
            }
        }
    }
}

// ---------------- Flash attention: LDS-shared K/V, ping-pong double-buffer ----------------
// Grid 1024 x 256. id = bh%8 + 8*(pair + 16*(bh/8)): per-XCD head residency.
// Block handles q-tiles {pair, 31-pair}. K/V staged via global_load_lds into alternating
// buffers; prefetch of tile jt+1 issues before compute on jt -> staging latency overlaps
// compute; ONE barrier per K-tile (the barrier's vmcnt drain lands the prefetch).
__global__ __launch_bounds__(256) void flash_attn_kernel(const bf16* __restrict__ qk,
                                                         const bf16* __restrict__ vt,
                                                         bf16* __restrict__ o) {
    const int id   = blockIdx.x;
    const int bhl  = id & 7;
    const int rest = id >> 3;
    const int pair = rest & 15;
    const int bhh  = rest >> 4;
    const int bh   = bhh * 8 + bhl;
    const int b    = bh >> 4;
    const int h    = bh & 15;
    const int wave = threadIdx.x >> 6;
    const int lane = threadIdx.x & 63;
    const int quad = lane >> 4;
    const int l16  = lane & 15;

    __shared__ __align__(16) bf16 sK[2][64 * 64];   // [buf][key][dh], xor-swizzled chunks
    __shared__ __align__(16) bf16 sV[2][64 * 64];   // [buf][dh][key], xor-swizzled chunks
    __shared__ bf16 pbuf[4][16][68];

    const bf16* kbase = qk + (size_t)(b * SEQ) * 2048 + 1024 + h * D_HEAD;
    const bf16* vbase = vt + ((size_t)(bh * D_HEAD) << 11);   // [dh][S]

    const int lrow   = lane >> 3;              // 0..7
    const int lchunk = (lane & 7) ^ lrow;      // gather-side xor swizzle
    const int xr     = l16 & 7;                // read-side xor

    auto stage = [&](int j0, int buf) {
        const bf16* gk = kbase + (size_t)(j0 + wave * 16 + lrow) * 2048 + lchunk * 8;
        const bf16* gv = vbase + (size_t)(wave * 16 + lrow) * 2048 + j0 + lchunk * 8;
        load16_lds(gk,            &sK[buf][(wave * 16) * 64]);
        load16_lds(gk + 8 * 2048, &sK[buf][(wave * 16 + 8) * 64]);
        load16_lds(gv,            &sV[buf][(wave * 16) * 64]);
        load16_lds(gv + 8 * 2048, &sV[buf][(wave * 16 + 8) * 64]);
    };

    bf16x8 ones;
#pragma unroll
    for (int i = 0; i < 8; ++i) ones[i] = (bf16)1.0f;

    for (int half = 0; half < 2; ++half) {
        const int qtile = half ? 31 - pair : pair;
        const int q0 = qtile * 64 + wave * 16;
        const size_t qrow = (size_t)(b * SEQ + q0 + l16) * 2048 + h * D_HEAD;
        bf16x8 qf0 = *reinterpret_cast<const bf16x8*>(qk + qrow + quad * 8);
        bf16x8 qf1 = *reinterpret_cast<const bf16x8*>(qk + qrow + 32 + quad * 8);

        f32x4 o_acc[4] = {(f32x4)(0.f), (f32x4)(0.f), (f32x4)(0.f), (f32x4)(0.f)};
        float m_q = -1e30f;
        float l_r[4] = {0.f, 0.f, 0.f, 0.f};

        stage(0, 0);
        __syncthreads();

        for (int jt = 0; jt <= qtile; ++jt) {
            const int j0 = jt * 64;
            const int cur = jt & 1;
            if (jt < qtile) stage(j0 + 64, cur ^ 1);   // async prefetch into other buffer

            const bf16* sKc = sK[cur];
            const bf16* sVc = sV[cur];

            f32x4 s_acc[4] = {(f32x4)(0.f), (f32x4)(0.f), (f32x4)(0.f), (f32x4)(0.f)};
#pragma unroll
            for (int nb = 0; nb < 4; ++nb) {
                const int row = nb * 16 + l16;
                const int slot = quad ^ xr;
                bf16x8 kf0 = *reinterpret_cast<const bf16x8*>(&sKc[row * 64 + slot * 8]);
                bf16x8 kf1 = *reinterpret_cast<const bf16x8*>(&sKc[row * 64 + (slot ^ 4) * 8]);
                s_acc[nb] = __builtin_amdgcn_mfma_f32_16x16x32_bf16(qf0, kf0, s_acc[nb], 0, 0, 0);
                s_acc[nb] = __builtin_amdgcn_mfma_f32_16x16x32_bf16(qf1, kf1, s_acc[nb], 0, 0, 0);
            }
            const bool diag = (jt == qtile);
            float sv[4][4];
            float mx = -1e30f;
#pragma unroll
            for (int nb = 0; nb < 4; ++nb) {
                const int key = j0 + nb * 16 + l16;
#pragma unroll
                for (int r = 0; r < 4; ++r) {
                    float s = s_acc[nb][r];
                    if (diag && key > q0 + quad * 4 + r) s = -1e30f;
                    sv[nb][r] = s;
                    mx = fmaxf(mx, s);
                }
            }
#pragma unroll
            for (int off = 1; off < 16; off <<= 1) mx = fmaxf(mx, __shfl_xor(mx, off, 64));
            const float mn = fmaxf(m_q, mx);
            const float alpha = __expf(m_q - mn);
            m_q = mn;
#pragma unroll
            for (int nb = 0; nb < 4; ++nb)
#pragma unroll
                for (int r = 0; r < 4; ++r)
                    pbuf[wave][quad * 4 + r][nb * 16 + l16] = (bf16)__expf(sv[nb][r] - mn);
#pragma unroll
            for (int r = 0; r < 4; ++r) l_r[r] *= alpha;
#pragma unroll
            for (int nb = 0; nb < 4; ++nb) o_acc[nb] *= alpha;
            bf16x8 pf0 = *reinterpret_cast<const bf16x8*>(&pbuf[wave][l16][quad * 8]);
            bf16x8 pf1 = *reinterpret_cast<const bf16x8*>(&pbuf[wave][l16][32 + quad * 8]);
            f32x4 lt = (f32x4)(0.f);
            lt = __builtin_amdgcn_mfma_f32_16x16x32_bf16(pf0, ones, lt, 0, 0, 0);
            lt = __builtin_amdgcn_mfma_f32_16x16x32_bf16(pf1, ones, lt, 0, 0, 0);
#pragma unroll
            for (int r = 0; r < 4; ++r) l_r[r] += lt[r];
#pragma unroll
            for (int nb = 0; nb < 4; ++nb) {
                const int row = nb * 16 + l16;
                const int slot = quad ^ xr;
                bf16x8 vf0 = *reinterpret_cast<const bf16x8*>(&sVc[row * 64 + slot * 8]);
                bf16x8 vf1 = *reinterpret_cast<const bf16x8*>(&sVc[row * 64 + (slot ^ 4) * 8]);
                o_acc[nb] = __builtin_amdgcn_mfma_f32_16x16x32_bf16(pf0, vf0, o_acc[nb], 0, 0, 0);
                o_acc[nb] = __builtin_amdgcn_mfma_f32_16x16x32_bf16(pf1, vf1, o_acc[nb], 0, 0, 0);
            }
            __syncthreads();   // all waves done with cur; prefetch landed (vmcnt drain)
        }
#pragma unroll
        for (int nb = 0; nb < 4; ++nb) {
#pragma unroll
            for (int r = 0; r < 4; ++r) {
                const int qrow_g = q0 + quad * 4 + r;
                o[(size_t)(b * SEQ + qrow_g) * D_MODEL + h * D_HEAD + nb * 16 + l16] =
                    (bf16)(o_acc[nb][r] / l_r[r]);
            }
        }
    }
}

// ---------------- launch ----------------
// fp32 I/O. resid lives in d_out. Workspace (lifetime-aliased):
//   [0,24)   MB : bf16 weights wq|wk|wv (=wqkv) |wo|fc1|fc2
//   [24,40)  MB : n1 -> attn -> hid(start)
//   [40,72)  MB : qk [8192,2048] (dead after flash)
//   [72,88)  MB : vT (dead after flash)
//   MLP: if ws >= 104 MB: hid = [24,88), n2 = [88,104); else 2-chunk, n2 = [72,88).
extern "C" void kernel_launch(void* const* d_in, const int* in_sizes, int n_in,
                              void* d_out, int out_size, void* d_ws, size_t ws_size,
                              hipStream_t stream) {
    const float* x      = (const float*)d_in[0];
    const float* gamma1 = (const float*)d_in[1];
    const float* beta1  = (const float*)d_in[2];
    const float* wq     = (const float*)d_in[3];
    const float* wk     = (const float*)d_in[4];
    const float* wv     = (const float*)d_in[5];
    const float* wo     = (const float*)d_in[6];
    const float* gamma2 = (const float*)d_in[7];
    const float* beta2  = (const float*)d_in[8];
    const float* fc1    = (const float*)d_in[9];
    const float* fc2    = (const float*)d_in[10];
    float* out = (float*)d_out;

    const size_t WSMALL = (size_t)N_HEADS * D_HEAD * D_MODEL;  // 1,048,576
    const size_t WFF    = (size_t)D_FF * D_MODEL;              // 4,194,304
    const size_t RD     = (size_t)ROWS * D_MODEL;              // 8,388,608

    char* wsb = (char*)d_ws;
    bf16* wq_b  = (bf16*)(wsb);           // wq|wk|wv contiguous = wqkv [3072,1024]
    bf16* wk_b  = wq_b + WSMALL;
    bf16* wv_b  = wk_b + WSMALL;
    bf16* wo_b  = wv_b + WSMALL;
    bf16* fc1_b = wo_b + WSMALL;
    bf16* fc2_b = fc1_b + WFF;            // ends at 24 MB
    bf16* slotA = fc2_b + WFF;            // [24,40): n1 -> attn -> hid
    bf16* qkb   = slotA + RD;             // [40,72): q|k stride-2048
    bf16* vtb   = qkb + 2 * RD;           // [72,88)

    bf16* n1    = slotA;
    bf16* attnb = slotA;
    bf16* hid   = slotA;
    float* resid = out;

    const size_t need_single = (size_t)(24 + 64 + 16) * 1024 * 1024;
    const bool single = ws_size >= need_single;
    bf16* n2 = single ? (bf16*)(wsb + (size_t)88 * 1024 * 1024) : vtb;

    // weight conversion fp32 -> bf16
    f2b4_kernel<<<dim3(64, 4), 256, 0, stream>>>(wq, wk, wv, wo, wq_b, wk_b, wv_b, wo_b, (int)WSMALL);
    f2b2_kernel<<<dim3(256, 2), 256, 0, stream>>>(fc1, fc2, fc1_b, fc2_b, (int)WFF);

    // LN1
    ln_kernel<<<ROWS, 256, 0, stream>>>(x, gamma1, beta1, n1);
    // fused QKV (1D XCD-affine grid): q (pre-scaled 1/8)|k -> qkb, v -> vtb transposed
    gemm_mt<4, 128, bf16><<<(3072 / 128) * (ROWS / 128), 256, 0, stream>>>(n1, wq_b, qkb, nullptr, vtb, ROWS, 3072, D_MODEL);
    // flash attention (LDS ping-pong, XCD-affine)
    flash_attn_kernel<<<1024, 256, 0, stream>>>(qkb, vtb, attnb);
    // resid(d_out) = x + attn @ wo^T
    gemm_mt<2, 64, float><<<(D_MODEL / 64) * (ROWS / 128), 256, 0, stream>>>(attnb, wo_b, resid, x, nullptr, ROWS, D_MODEL, D_MODEL);
    // LN2
    ln_kernel<<<ROWS, 256, 0, stream>>>(resid, gamma2, beta2, n2);

    if (single) {
        gemm_mt<1, 128, bf16><<<(D_FF / 128) * (ROWS / 128), 256, 0, stream>>>(n2, fc1_b, hid, nullptr, nullptr, ROWS, D_FF, D_MODEL);
        gemm_mt<2, 64, float><<<(D_MODEL / 64) * (ROWS / 128), 256, 0, stream>>>(hid, fc2_b, out, resid, nullptr, ROWS, D_MODEL, D_FF);
    } else {
        const int CHUNK = 4096;   // hid chunk = 32 MB in [24,56); CHUNK/128 = 32 (div by 8 ok)
        for (int c = 0; c < ROWS / CHUNK; ++c) {
            const bf16*  n2c    = n2    + (size_t)c * CHUNK * D_MODEL;
            const float* residc = resid + (size_t)c * CHUNK * D_MODEL;
            float*       outc   = out   + (size_t)c * CHUNK * D_MODEL;
            gemm_mt<1, 128, bf16><<<(D_FF / 128) * (CHUNK / 128), 256, 0, stream>>>(n2c, fc1_b, hid, nullptr, nullptr, CHUNK, D_FF, D_MODEL);
            gemm_mt<2, 64, float><<<(D_MODEL / 64) * (CHUNK / 128), 256, 0, stream>>>(hid, fc2_b, outc, residc, nullptr, CHUNK, D_MODEL, D_FF);
        }
    }
}